// Round 12
// baseline (281.334 us; speedup 1.0000x reference)
//
#include <hip/hip_runtime.h>
#include <hip/hip_bf16.h>
#include <cstdint>

// Problem constants
constexpr int BB = 64;    // batch
constexpr int TT = 12;    // time
constexpr int NN = 512;   // nodes
constexpr int FF = 64;    // features
constexpr int UU = 64;    // units
constexpr int MAXNZ = 128;
constexpr int MCH = 16;   // m-columns per k_product_E block

// ---------------------------------------------------------------------------
// Workspace layout (bytes):
//   floats: lhs 0 / rhs 393216f / beT 786432f / evals 1048576f
//   ints:   nnz 20971520 / cidx 20973568 / ccnt 21235712 / colj 21237760
//   xT (B,N,T,F) bf16 : 21516288, 50331648 B
//   ST (B,N,N) bf16, m-major (ST[b][m][k]) : 71847936, 33554432 B
// ---------------------------------------------------------------------------
constexpr size_t OF_LHS   = 0;
constexpr size_t OF_RHS   = 393216;
constexpr size_t OF_BET   = 786432;
constexpr size_t OF_EVALS = 1048576;
constexpr size_t OB_NNZ   = 20971520;
constexpr size_t OB_CIDX  = 20973568;
constexpr size_t OB_CCNT  = 21235712;
constexpr size_t OB_COLJ  = 21237760;
constexpr size_t OB_XT    = 21516288;
constexpr size_t XT_BYTES = (size_t)BB * NN * TT * FF * 2;  // 50331648
constexpr size_t OB_ST    = 71847936;
constexpr size_t ST_BYTES = (size_t)BB * NN * NN * 2;       // 33554432

__device__ __forceinline__ float wred_sum(float v) {
  #pragma unroll
  for (int off = 32; off; off >>= 1) v += __shfl_xor(v, off, 64);
  return v;
}

__device__ __forceinline__ float bflo(unsigned u) {
  return __uint_as_float(u << 16);
}
__device__ __forceinline__ float bfhi(unsigned u) {
  return __uint_as_float(u & 0xFFFF0000u);
}

// ---------------------------------------------------------------------------
// Kernel 1: lhs/rhs reductions; also writes xT[b][n][t][f] bf16
// ---------------------------------------------------------------------------
__global__ __launch_bounds__(256) void k_lhs_rhs(
    const float* __restrict__ x, const float* __restrict__ W1,
    const float* __restrict__ W2, const float* __restrict__ W3,
    float* __restrict__ lhs, float* __restrict__ rhsS,
    unsigned short* __restrict__ xT)   // may be null
{
  int unit = blockIdx.x * 4 + (threadIdx.x >> 6);   // b*512 + n
  int lane = threadIdx.x & 63;
  int b = unit >> 9, n = unit & 511;

  const float* xb = x + ((size_t)b * TT * NN + n) * FF + lane;
  float xv[12];
  #pragma unroll
  for (int t = 0; t < 12; ++t) xv[t] = xb[(size_t)t * NN * FF];

  if (xT) {
    unsigned short* xo = xT + (size_t)unit * (TT * FF) + lane;
    #pragma unroll
    for (int t = 0; t < 12; ++t) {
      __hip_bfloat16 h = __float2bfloat16(xv[t]);   // RTNE
      xo[t * FF] = *reinterpret_cast<unsigned short*>(&h);
    }
  }

  float r1 = 0.f;
  #pragma unroll
  for (int t = 0; t < 12; ++t) r1 += xv[t] * W1[t];

  float w3 = W3[lane];

  float myl = 0.f, myr = 0.f;
  #pragma unroll
  for (int t = 0; t < 12; ++t) {
    float a = r1 * W2[lane * 12 + t];
    float c = xv[t] * w3;
    a = wred_sum(a);
    c = wred_sum(c);
    if (lane == t) { myl = a; myr = c; }
  }
  if (lane < 12) {
    lhs[(size_t)unit * 12 + lane]  = myl;
    rhsS[(size_t)unit * 12 + lane] = myr;
  }
}

// ---------------------------------------------------------------------------
// Kernel 2: beT[m,k] = be[k,m]
// ---------------------------------------------------------------------------
__global__ __launch_bounds__(256) void k_transpose(
    const float* __restrict__ be, float* __restrict__ beT)
{
  int i = blockIdx.x * 256 + threadIdx.x;  // 262144 total
  int k = i >> 9, m = i & 511;
  beT[m * 512 + k] = be[i];
}

// ---------------------------------------------------------------------------
// Kernel 3: row-wise compaction of mask A (deterministic, ordered by m)
// ---------------------------------------------------------------------------
__global__ void k_build_idx(const float* __restrict__ A,
                            int* __restrict__ nnz, int* __restrict__ cidx)
{
  int j = blockIdx.x;
  int lane = threadIdx.x;  // 64 threads
  unsigned long long lt = (1ull << lane) - 1ull;
  int base = 0;
  for (int c = 0; c < 8; ++c) {
    int m = c * 64 + lane;
    bool p = A[(size_t)j * 512 + m] > 0.5f;
    unsigned long long mask = __ballot(p);
    int pos = base + __popcll(mask & lt);
    if (p && pos < MAXNZ) cidx[j * MAXNZ + pos] = m;
    base += __popcll(mask);
  }
  if (lane == 0) nnz[j] = base > MAXNZ ? MAXNZ : base;
}

// ---------------------------------------------------------------------------
// Kernel 4: column lists
// ---------------------------------------------------------------------------
__global__ void k_build_col(const int* __restrict__ nnz, const int* __restrict__ cidx,
                            int* __restrict__ ccnt, unsigned* __restrict__ colj)
{
  int j = blockIdx.x;
  int lane = threadIdx.x;
  int cnt = nnz[j];
  for (int s = lane; s < cnt; s += 64) {
    int m = cidx[j * MAXNZ + s];
    int pos = atomicAdd(&ccnt[m], 1);
    if (pos < MAXNZ) colj[m * MAXNZ + pos] = (unsigned)j | ((unsigned)s << 16);
  }
}

// ---------------------------------------------------------------------------
// Kernel 5a (fast path): sigmoid columns -> ST[b][m][k] bf16.
//   Block (b, 16 m's). lhsL stride-13 (conflict-free); thread covers
//   k = tid, tid+256 per m; coalesced beT reads and 2-B ST writes.
// ---------------------------------------------------------------------------
__global__ __launch_bounds__(256) void k_sigmoid(
    const float* __restrict__ lhs, const float* __restrict__ rhsS,
    const float* __restrict__ beT, unsigned short* __restrict__ ST)
{
  int b  = blockIdx.x;   // 0..63
  int mc = blockIdx.y;   // 0..31

  __shared__ float lhsL[512 * 13];
  __shared__ float rh[16 * 12];

  int tid = threadIdx.x;
  const float* src = lhs + (size_t)b * 512 * 12;
  for (int i = tid; i < 6144; i += 256) {
    int k = i / 12, t = i - k * 12;
    lhsL[k * 13 + t] = src[i];
  }
  if (tid < 192) rh[tid] = rhsS[((size_t)b * 512 + mc * 16) * 12 + tid];
  __syncthreads();

  int k0 = tid, k1 = tid + 256;
  const float* l0 = &lhsL[k0 * 13];
  const float* l1 = &lhsL[k1 * 13];

  #pragma unroll 4
  for (int mm = 0; mm < 16; ++mm) {
    int m = mc * 16 + mm;
    const float* rw = &rh[mm * 12];
    float p0 = beT[m * 512 + k0];
    float p1 = beT[m * 512 + k1];
    #pragma unroll
    for (int t = 0; t < 12; ++t) {
      p0 = fmaf(l0[t], rw[t], p0);
      p1 = fmaf(l1[t], rw[t], p1);
    }
    float s0 = 1.0f / (1.0f + __expf(-p0));
    float s1 = 1.0f / (1.0f + __expf(-p1));
    __hip_bfloat16 h0 = __float2bfloat16(s0);
    __hip_bfloat16 h1 = __float2bfloat16(s1);
    unsigned short* dst = ST + ((size_t)(b * NN + m)) * NN;
    dst[k0] = *reinterpret_cast<unsigned short*>(&h0);
    dst[k1] = *reinterpret_cast<unsigned short*>(&h1);
  }
}

// ---------------------------------------------------------------------------
// Kernel 5b (fast path): E at masked entries, batched over b for Ve reuse.
//   Block (m, b-half of 32). Two chunks of 16 batches staged in LDS
//   sf[16][516] f32 (pad 516: lanes (b16,q) -> banks 4*b16+q all distinct).
//   Per entry: lane (b16 = lane>>2, q = lane&3) dots 128 q-strided elements,
//   2-step shuffle reduce. Ve row read once per chunk per entry (L1/L2).
// ---------------------------------------------------------------------------
__global__ __launch_bounds__(256) void k_E_col(
    const unsigned short* __restrict__ ST, const float* __restrict__ Ve,
    const int* __restrict__ ccnt, const unsigned* __restrict__ colj,
    float* __restrict__ evals)
{
  int m  = blockIdx.x;   // 0..511
  int bh = blockIdx.y;   // 0..1 -> batches bh*32..bh*32+31

  __shared__ float sf[16][516];   // 33 KB

  int tid = threadIdx.x;
  int wv = tid >> 6, lane = tid & 63;
  int b16 = lane >> 2, q = lane & 3;

  int cnt = ccnt[m];
  if (cnt > MAXNZ) cnt = MAXNZ;

  for (int ch = 0; ch < 2; ++ch) {
    if (ch) __syncthreads();   // previous chunk's compute done
    // stage 16 batches' S columns (bf16 -> f32)
    {
      int bb  = tid & 15;           // batch within chunk
      int ks  = (tid >> 4) * 32;    // 32 k per thread
      const unsigned* src = reinterpret_cast<const unsigned*>(
          ST + ((size_t)((bh * 32 + ch * 16 + bb) * NN + m)) * NN) + (ks >> 1);
      float* dst = &sf[bb][ks];
      #pragma unroll
      for (int i = 0; i < 16; ++i) {
        unsigned u = src[i];
        dst[2 * i]     = bflo(u);
        dst[2 * i + 1] = bfhi(u);
      }
    }
    __syncthreads();

    for (int e = wv; e < cnt; e += 4) {
      unsigned pk = colj[m * MAXNZ + e];
      int j = pk & 0xffff, slot = (int)(pk >> 16);
      const float* vr = Ve + (size_t)j * 512 + q;
      const float* sr = &sf[b16][q];
      float a0 = 0.f, a1 = 0.f;
      #pragma unroll 16
      for (int kk = 0; kk < 64; ++kk) {
        a0 = fmaf(vr[4 * kk],        sr[4 * kk],        a0);
        a1 = fmaf(vr[4 * kk + 256],  sr[4 * kk + 256],  a1);
      }
      float acc = a0 + a1;
      acc += __shfl_xor(acc, 1, 64);
      acc += __shfl_xor(acc, 2, 64);
      if (q == 0)
        evals[((size_t)((bh * 32 + ch * 16 + b16) * NN) + j) * MAXNZ + slot] = acc;
    }
  }
}

// ---------------------------------------------------------------------------
// Kernel 5 (fallback): fused product+sigmoid+E (R10 version, 105 us)
// ---------------------------------------------------------------------------
__global__ __launch_bounds__(256) void k_product_E(
    const float* __restrict__ lhs, const float* __restrict__ rhsS,
    const float* __restrict__ beT, const float* __restrict__ Ve,
    const int* __restrict__ ccnt, const unsigned* __restrict__ colj,
    float* __restrict__ evals)
{
  int b  = blockIdx.x;
  int mc = blockIdx.y;

  __shared__ float lhsL[512 * 13];
  __shared__ float sL[4][512];
  __shared__ float rh[MCH * 12];

  int tid = threadIdx.x;
  const float* src = lhs + (size_t)b * 512 * 12;
  for (int i = tid; i < 6144; i += 256) {
    int k = i / 12, t = i - k * 12;
    lhsL[k * 13 + t] = src[i];
  }
  if (tid < MCH * 12) rh[tid] = rhsS[((size_t)b * 512 + mc * MCH) * 12 + tid];
  __syncthreads();

  int wave = tid >> 6, lane = tid & 63;
  int grp = lane >> 4, lg = lane & 15;

  for (int g = 0; g < MCH / 4; ++g) {
    if (g) __syncthreads();
    for (int i = tid; i < 4 * 512; i += 256) {
      int w = i >> 9, k = i & 511;
      int m = mc * MCH + g * 4 + w;
      float p = beT[m * 512 + k];
      const float* lr = &lhsL[k * 13];
      const float* rw = &rh[(g * 4 + w) * 12];
      #pragma unroll
      for (int t = 0; t < 12; ++t) p += lr[t] * rw[t];
      sL[w][k] = 1.0f / (1.0f + __expf(-p));
    }
    __syncthreads();

    int m = mc * MCH + g * 4 + wave;
    int cnt = ccnt[m];
    if (cnt > MAXNZ) cnt = MAXNZ;
    const float* sw = sL[wave];
    for (int e = grp; e < cnt; e += 4) {
      unsigned pk = colj[m * MAXNZ + e];
      int j = pk & 0xffff, slot = (int)(pk >> 16);
      const float* vr = Ve + (size_t)j * 512;
      float part = 0.f;
      #pragma unroll
      for (int kk = 0; kk < 32; ++kk)
        part = fmaf(vr[kk * 16 + lg], sw[kk * 16 + lg], part);
      #pragma unroll
      for (int off = 8; off; off >>= 1) part += __shfl_xor(part, off, 64);
      if (lg == 0) evals[((size_t)b * 512 + j) * MAXNZ + slot] = part;
    }
  }
}

// ---------------------------------------------------------------------------
// Kernel 6: masked softmax (unchanged)
// ---------------------------------------------------------------------------
__global__ __launch_bounds__(256) void k_softmax(
    const int* __restrict__ nnz, float* __restrict__ evals)
{
  int unit = blockIdx.x * 4 + (threadIdx.x >> 6);  // b*512 + j
  int lane = threadIdx.x & 63;
  int j = unit & 511;
  int cnt = nnz[j];
  float* ev = evals + (size_t)unit * MAXNZ;
  float v0 = lane < cnt        ? ev[lane]      : -__builtin_inff();
  float v1 = (lane + 64) < cnt ? ev[lane + 64] : -__builtin_inff();
  float mx = fmaxf(v0, v1);
  #pragma unroll
  for (int off = 32; off; off >>= 1) mx = fmaxf(mx, __shfl_xor(mx, off, 64));
  float e0 = lane < cnt        ? __expf(v0 - mx) : 0.f;
  float e1 = (lane + 64) < cnt ? __expf(v1 - mx) : 0.f;
  float s = wred_sum(e0 + e1);
  float inv = 1.0f / s;
  if (lane < cnt)        ev[lane]      = e0 * inv;
  if ((lane + 64) < cnt) ev[lane + 64] = e1 * inv;
}

// ---------------------------------------------------------------------------
// Kernel 7 (v10): wave per (b,j). xT imm-offset bf16 gather + f-tiled GEMM.
// ---------------------------------------------------------------------------
__global__ __launch_bounds__(256) void k_out10(
    const unsigned short* __restrict__ xT,
    const int* __restrict__ nnz, const int* __restrict__ cidx,
    const float* __restrict__ evals,
    const float* __restrict__ K, const float* __restrict__ bias,
    float* __restrict__ out)
{
  int tid = threadIdx.x;
  int wv = tid >> 6, lane = tid & 63;
  int bid = blockIdx.x;
  int sbid = (bid & 7) * 1024 + (bid >> 3);  // bijective on [0,8192)
  int unit = sbid * 4 + wv;                  // b*512 + j
  int b = unit >> 9, j = unit & 511;

  __shared__ float convL[4][12][64];
  __shared__ float valL[4][MAXNZ];
  __shared__ int   idxL[4][MAXNZ];

  int cnt = nnz[j];
  for (int s = lane; s < cnt; s += 64) {
    idxL[wv][s] = cidx[j * MAXNZ + s];
    valL[wv][s] = evals[(size_t)unit * MAXNZ + s];
  }

  float2 acc[6];
  #pragma unroll
  for (int i = 0; i < 6; ++i) acc[i] = make_float2(0.f, 0.f);

  const unsigned* xb = reinterpret_cast<const unsigned*>(
      xT + (size_t)b * NN * (TT * FF));

  int s = 0;
  for (; s + 1 < cnt; s += 2) {
    int   k0 = idxL[wv][s],     k1 = idxL[wv][s + 1];
    float v0 = valL[wv][s],     v1 = valL[wv][s + 1];
    const unsigned* p0 = xb + k0 * 384 + lane;
    const unsigned* p1 = xb + k1 * 384 + lane;
    unsigned a0 = p0[0],   a1 = p0[64],  a2 = p0[128],
             a3 = p0[192], a4 = p0[256], a5 = p0[320];
    unsigned c0 = p1[0],   c1 = p1[64],  c2 = p1[128],
             c3 = p1[192], c4 = p1[256], c5 = p1[320];
    acc[0].x = fmaf(v0, bflo(a0), acc[0].x); acc[0].y = fmaf(v0, bfhi(a0), acc[0].y);
    acc[1].x = fmaf(v0, bflo(a1), acc[1].x); acc[1].y = fmaf(v0, bfhi(a1), acc[1].y);
    acc[2].x = fmaf(v0, bflo(a2), acc[2].x); acc[2].y = fmaf(v0, bfhi(a2), acc[2].y);
    acc[3].x = fmaf(v0, bflo(a3), acc[3].x); acc[3].y = fmaf(v0, bfhi(a3), acc[3].y);
    acc[4].x = fmaf(v0, bflo(a4), acc[4].x); acc[4].y = fmaf(v0, bfhi(a4), acc[4].y);
    acc[5].x = fmaf(v0, bflo(a5), acc[5].x); acc[5].y = fmaf(v0, bfhi(a5), acc[5].y);
    acc[0].x = fmaf(v1, bflo(c0), acc[0].x); acc[0].y = fmaf(v1, bfhi(c0), acc[0].y);
    acc[1].x = fmaf(v1, bflo(c1), acc[1].x); acc[1].y = fmaf(v1, bfhi(c1), acc[1].y);
    acc[2].x = fmaf(v1, bflo(c2), acc[2].x); acc[2].y = fmaf(v1, bfhi(c2), acc[2].y);
    acc[3].x = fmaf(v1, bflo(c3), acc[3].x); acc[3].y = fmaf(v1, bfhi(c3), acc[3].y);
    acc[4].x = fmaf(v1, bflo(c4), acc[4].x); acc[4].y = fmaf(v1, bfhi(c4), acc[4].y);
    acc[5].x = fmaf(v1, bflo(c5), acc[5].x); acc[5].y = fmaf(v1, bfhi(c5), acc[5].y);
  }
  if (s < cnt) {
    int   k0 = idxL[wv][s];
    float v0 = valL[wv][s];
    const unsigned* p0 = xb + k0 * 384 + lane;
    unsigned a0 = p0[0],   a1 = p0[64],  a2 = p0[128],
             a3 = p0[192], a4 = p0[256], a5 = p0[320];
    acc[0].x = fmaf(v0, bflo(a0), acc[0].x); acc[0].y = fmaf(v0, bfhi(a0), acc[0].y);
    acc[1].x = fmaf(v0, bflo(a1), acc[1].x); acc[1].y = fmaf(v0, bfhi(a1), acc[1].y);
    acc[2].x = fmaf(v0, bflo(a2), acc[2].x); acc[2].y = fmaf(v0, bfhi(a2), acc[2].y);
    acc[3].x = fmaf(v0, bflo(a3), acc[3].x); acc[3].y = fmaf(v0, bfhi(a3), acc[3].y);
    acc[4].x = fmaf(v0, bflo(a4), acc[4].x); acc[4].y = fmaf(v0, bfhi(a4), acc[4].y);
    acc[5].x = fmaf(v0, bflo(a5), acc[5].x); acc[5].y = fmaf(v0, bfhi(a5), acc[5].y);
  }

  int half = lane >> 5, fl = lane & 31;
  #pragma unroll
  for (int i = 0; i < 6; ++i)
    *(float2*)&convL[wv][2 * i + half][fl * 2] = acc[i];

  float bs = bias[lane];
  float o[12];
  #pragma unroll
  for (int t = 0; t < 12; ++t) o[t] = bs;

  __syncthreads();

  #pragma unroll
  for (int ft = 0; ft < 4; ++ft) {
    float kc[16];
    #pragma unroll
    for (int i = 0; i < 16; ++i) kc[i] = K[(ft * 16 + i) * 64 + lane];
    #pragma unroll
    for (int t = 0; t < 12; ++t) {
      const float4* cv = (const float4*)&convL[wv][t][ft * 16];
      float4 c0 = cv[0], c1 = cv[1], c2 = cv[2], c3 = cv[3];
      o[t] += c0.x * kc[0]  + c0.y * kc[1]  + c0.z * kc[2]  + c0.w * kc[3]
            + c1.x * kc[4]  + c1.y * kc[5]  + c1.z * kc[6]  + c1.w * kc[7]
            + c2.x * kc[8]  + c2.y * kc[9]  + c2.z * kc[10] + c2.w * kc[11]
            + c3.x * kc[12] + c3.y * kc[13] + c3.z * kc[14] + c3.w * kc[15];
    }
  }

  #pragma unroll
  for (int t = 0; t < 12; ++t)
    out[((size_t)(b * TT + t) * NN + j) * UU + lane] = o[t];
}

// ---------------------------------------------------------------------------
// Kernel 7 fallback (fp32 scalar gather + f-tiled phase B) — if ws small
// ---------------------------------------------------------------------------
__global__ __launch_bounds__(256) void k_out3f(
    const float* __restrict__ x,
    const int* __restrict__ nnz, const int* __restrict__ cidx,
    const float* __restrict__ evals,
    const float* __restrict__ K, const float* __restrict__ bias,
    float* __restrict__ out)
{
  int wv = threadIdx.x >> 6, lane = threadIdx.x & 63;
  int bid = blockIdx.x;
  int sbid = (bid & 7) * 1024 + (bid >> 3);
  int unit = sbid * 4 + wv;
  int b = unit >> 9, j = unit & 511;

  __shared__ float convL[4][12][64];
  __shared__ float valL[4][MAXNZ];
  __shared__ int   idxL[4][MAXNZ];

  int cnt = nnz[j];
  for (int s = lane; s < cnt; s += 64) {
    idxL[wv][s] = cidx[j * MAXNZ + s];
    valL[wv][s] = evals[(size_t)unit * MAXNZ + s];
  }

  float acc[12];
  #pragma unroll
  for (int t = 0; t < 12; ++t) acc[t] = 0.f;

  const float* xb = x + (size_t)b * TT * NN * FF + lane;
  for (int s = 0; s < cnt; ++s) {
    float v = valL[wv][s];
    const float* xk = xb + (size_t)idxL[wv][s] * FF;
    #pragma unroll
    for (int t = 0; t < 12; ++t)
      acc[t] = fmaf(v, xk[(size_t)t * NN * FF], acc[t]);
  }
  #pragma unroll
  for (int t = 0; t < 12; ++t) convL[wv][t][lane] = acc[t];

  float bs = bias[lane];
  float o[12];
  #pragma unroll
  for (int t = 0; t < 12; ++t) o[t] = bs;
  __syncthreads();

  #pragma unroll
  for (int ft = 0; ft < 4; ++ft) {
    float kc[16];
    #pragma unroll
    for (int i = 0; i < 16; ++i) kc[i] = K[(ft * 16 + i) * 64 + lane];
    #pragma unroll
    for (int t = 0; t < 12; ++t) {
      const float4* cv = (const float4*)&convL[wv][t][ft * 16];
      float4 c0 = cv[0], c1 = cv[1], c2 = cv[2], c3 = cv[3];
      o[t] += c0.x * kc[0]  + c0.y * kc[1]  + c0.z * kc[2]  + c0.w * kc[3]
            + c1.x * kc[4]  + c1.y * kc[5]  + c1.z * kc[6]  + c1.w * kc[7]
            + c2.x * kc[8]  + c2.y * kc[9]  + c2.z * kc[10] + c2.w * kc[11]
            + c3.x * kc[12] + c3.y * kc[13] + c3.z * kc[14] + c3.w * kc[15];
    }
  }

  #pragma unroll
  for (int t = 0; t < 12; ++t)
    out[((size_t)(b * TT + t) * NN + j) * UU + lane] = o[t];
}

// ---------------------------------------------------------------------------
extern "C" void kernel_launch(void* const* d_in, const int* in_sizes, int n_in,
                              void* d_out, int out_size, void* d_ws, size_t ws_size,
                              hipStream_t stream)
{
  const float* x    = (const float*)d_in[0];  // (B,T,N,F)
  const float* A    = (const float*)d_in[1];  // (N,N)
  const float* W1   = (const float*)d_in[2];  // (T,1)
  const float* W2   = (const float*)d_in[3];  // (F,T)
  const float* W3   = (const float*)d_in[4];  // (F,1)
  const float* Ve   = (const float*)d_in[5];  // (N,N)
  const float* be   = (const float*)d_in[6];  // (N,N)
  const float* K    = (const float*)d_in[7];  // (F,U)
  const float* bias = (const float*)d_in[8];  // (U,)
  float* out = (float*)d_out;

  char* ws = (char*)d_ws;
  float* lhs   = (float*)ws + OF_LHS;
  float* rhsS  = (float*)ws + OF_RHS;
  float* beT   = (float*)ws + OF_BET;
  float* evals = (float*)ws + OF_EVALS;
  int*      nnz  = (int*)(ws + OB_NNZ);
  int*      cidx = (int*)(ws + OB_CIDX);
  int*      ccnt = (int*)(ws + OB_CCNT);
  unsigned* colj = (unsigned*)(ws + OB_COLJ);
  unsigned short* xT = (unsigned short*)(ws + OB_XT);
  unsigned short* ST = (unsigned short*)(ws + OB_ST);

  const bool use_xt    = ws_size >= OB_XT + XT_BYTES;
  const bool use_fastE = ws_size >= OB_ST + ST_BYTES;

  hipMemsetAsync(ccnt, 0, NN * sizeof(int), stream);

  // 1. lhs / rhs (+ transposed bf16 copy of x)
  k_lhs_rhs<<<dim3(BB * NN / 4), dim3(256), 0, stream>>>(
      x, W1, W2, W3, lhs, rhsS, use_xt ? xT : nullptr);
  // 2. transpose be
  k_transpose<<<dim3(NN * NN / 256), dim3(256), 0, stream>>>(be, beT);
  // 3. row index lists
  k_build_idx<<<dim3(NN), dim3(64), 0, stream>>>(A, nnz, cidx);
  // 4. column lists
  k_build_col<<<dim3(NN), dim3(64), 0, stream>>>(nnz, cidx, ccnt, colj);
  // 5. product + sigmoid + masked E
  if (use_fastE) {
    k_sigmoid<<<dim3(BB, NN / 16), dim3(256), 0, stream>>>(lhs, rhsS, beT, ST);
    k_E_col<<<dim3(NN, 2), dim3(256), 0, stream>>>(ST, Ve, ccnt, colj, evals);
  } else {
    k_product_E<<<dim3(BB, NN / MCH), dim3(256), 0, stream>>>(lhs, rhsS, beT, Ve, ccnt, colj, evals);
  }
  // 6. softmax over slots
  k_softmax<<<dim3(BB * NN / 4), dim3(256), 0, stream>>>(nnz, evals);
  // 7. sparse conv + f-tiled output GEMM
  if (use_xt)
    k_out10<<<dim3(BB * NN / 4), dim3(256), 0, stream>>>(xT, nnz, cidx, evals, K, bias, out);
  else
    k_out3f<<<dim3(BB * NN / 4), dim3(256), 0, stream>>>(x, nnz, cidx, evals, K, bias, out);
}

// Round 13
// 270.327 us; speedup vs baseline: 1.0407x; 1.0407x over previous
//
#include <hip/hip_runtime.h>
#include <hip/hip_bf16.h>
#include <cstdint>

// Problem constants
constexpr int BB = 64;    // batch
constexpr int TT = 12;    // time
constexpr int NN = 512;   // nodes
constexpr int FF = 64;    // features
constexpr int UU = 64;    // units
constexpr int MAXNZ = 128;
constexpr int MCH = 16;   // m-columns per k_product_E block

// ---------------------------------------------------------------------------
// Workspace layout (bytes):
//   floats: lhs 0 / rhs 393216f / beT 786432f / evals 1048576f
//   ints:   nnz 20971520 / cidx 20973568 / ccnt 21235712 / colj 21237760
//   xT (B,N,T,F) bf16 : 21516288, 50331648 B
//   ST (B,N,N) bf16, m-major (ST[b][m][k]) : 71847936, 33554432 B
// ---------------------------------------------------------------------------
constexpr size_t OF_LHS   = 0;
constexpr size_t OF_RHS   = 393216;
constexpr size_t OF_BET   = 786432;
constexpr size_t OF_EVALS = 1048576;
constexpr size_t OB_NNZ   = 20971520;
constexpr size_t OB_CIDX  = 20973568;
constexpr size_t OB_CCNT  = 21235712;
constexpr size_t OB_COLJ  = 21237760;
constexpr size_t OB_XT    = 21516288;
constexpr size_t XT_BYTES = (size_t)BB * NN * TT * FF * 2;  // 50331648
constexpr size_t OB_ST    = 71847936;
constexpr size_t ST_BYTES = (size_t)BB * NN * NN * 2;       // 33554432

__device__ __forceinline__ float wred_sum(float v) {
  #pragma unroll
  for (int off = 32; off; off >>= 1) v += __shfl_xor(v, off, 64);
  return v;
}

__device__ __forceinline__ float bflo(unsigned u) {
  return __uint_as_float(u << 16);
}
__device__ __forceinline__ float bfhi(unsigned u) {
  return __uint_as_float(u & 0xFFFF0000u);
}

// ---------------------------------------------------------------------------
// Kernel 1: lhs/rhs reductions; also writes xT[b][n][t][f] bf16
// ---------------------------------------------------------------------------
__global__ __launch_bounds__(256) void k_lhs_rhs(
    const float* __restrict__ x, const float* __restrict__ W1,
    const float* __restrict__ W2, const float* __restrict__ W3,
    float* __restrict__ lhs, float* __restrict__ rhsS,
    unsigned short* __restrict__ xT)   // may be null
{
  int unit = blockIdx.x * 4 + (threadIdx.x >> 6);   // b*512 + n
  int lane = threadIdx.x & 63;
  int b = unit >> 9, n = unit & 511;

  const float* xb = x + ((size_t)b * TT * NN + n) * FF + lane;
  float xv[12];
  #pragma unroll
  for (int t = 0; t < 12; ++t) xv[t] = xb[(size_t)t * NN * FF];

  if (xT) {
    unsigned short* xo = xT + (size_t)unit * (TT * FF) + lane;
    #pragma unroll
    for (int t = 0; t < 12; ++t) {
      __hip_bfloat16 h = __float2bfloat16(xv[t]);   // RTNE
      xo[t * FF] = *reinterpret_cast<unsigned short*>(&h);
    }
  }

  float r1 = 0.f;
  #pragma unroll
  for (int t = 0; t < 12; ++t) r1 += xv[t] * W1[t];

  float w3 = W3[lane];

  float myl = 0.f, myr = 0.f;
  #pragma unroll
  for (int t = 0; t < 12; ++t) {
    float a = r1 * W2[lane * 12 + t];
    float c = xv[t] * w3;
    a = wred_sum(a);
    c = wred_sum(c);
    if (lane == t) { myl = a; myr = c; }
  }
  if (lane < 12) {
    lhs[(size_t)unit * 12 + lane]  = myl;
    rhsS[(size_t)unit * 12 + lane] = myr;
  }
}

// ---------------------------------------------------------------------------
// Kernel 2: beT[m,k] = be[k,m]
// ---------------------------------------------------------------------------
__global__ __launch_bounds__(256) void k_transpose(
    const float* __restrict__ be, float* __restrict__ beT)
{
  int i = blockIdx.x * 256 + threadIdx.x;  // 262144 total
  int k = i >> 9, m = i & 511;
  beT[m * 512 + k] = be[i];
}

// ---------------------------------------------------------------------------
// Kernel 3: row-wise compaction of mask A (deterministic, ordered by m)
// ---------------------------------------------------------------------------
__global__ void k_build_idx(const float* __restrict__ A,
                            int* __restrict__ nnz, int* __restrict__ cidx)
{
  int j = blockIdx.x;
  int lane = threadIdx.x;  // 64 threads
  unsigned long long lt = (1ull << lane) - 1ull;
  int base = 0;
  for (int c = 0; c < 8; ++c) {
    int m = c * 64 + lane;
    bool p = A[(size_t)j * 512 + m] > 0.5f;
    unsigned long long mask = __ballot(p);
    int pos = base + __popcll(mask & lt);
    if (p && pos < MAXNZ) cidx[j * MAXNZ + pos] = m;
    base += __popcll(mask);
  }
  if (lane == 0) nnz[j] = base > MAXNZ ? MAXNZ : base;
}

// ---------------------------------------------------------------------------
// Kernel 4: column lists
// ---------------------------------------------------------------------------
__global__ void k_build_col(const int* __restrict__ nnz, const int* __restrict__ cidx,
                            int* __restrict__ ccnt, unsigned* __restrict__ colj)
{
  int j = blockIdx.x;
  int lane = threadIdx.x;
  int cnt = nnz[j];
  for (int s = lane; s < cnt; s += 64) {
    int m = cidx[j * MAXNZ + s];
    int pos = atomicAdd(&ccnt[m], 1);
    if (pos < MAXNZ) colj[m * MAXNZ + pos] = (unsigned)j | ((unsigned)s << 16);
  }
}

// ---------------------------------------------------------------------------
// Kernel 5a: sigmoid columns -> ST[b][m][k] bf16 (unchanged from R12)
// ---------------------------------------------------------------------------
__global__ __launch_bounds__(256) void k_sigmoid(
    const float* __restrict__ lhs, const float* __restrict__ rhsS,
    const float* __restrict__ beT, unsigned short* __restrict__ ST)
{
  int b  = blockIdx.x;   // 0..63
  int mc = blockIdx.y;   // 0..31

  __shared__ float lhsL[512 * 13];
  __shared__ float rh[16 * 12];

  int tid = threadIdx.x;
  const float* src = lhs + (size_t)b * 512 * 12;
  for (int i = tid; i < 6144; i += 256) {
    int k = i / 12, t = i - k * 12;
    lhsL[k * 13 + t] = src[i];
  }
  if (tid < 192) rh[tid] = rhsS[((size_t)b * 512 + mc * 16) * 12 + tid];
  __syncthreads();

  int k0 = tid, k1 = tid + 256;
  const float* l0 = &lhsL[k0 * 13];
  const float* l1 = &lhsL[k1 * 13];

  #pragma unroll 4
  for (int mm = 0; mm < 16; ++mm) {
    int m = mc * 16 + mm;
    const float* rw = &rh[mm * 12];
    float p0 = beT[m * 512 + k0];
    float p1 = beT[m * 512 + k1];
    #pragma unroll
    for (int t = 0; t < 12; ++t) {
      p0 = fmaf(l0[t], rw[t], p0);
      p1 = fmaf(l1[t], rw[t], p1);
    }
    float s0 = 1.0f / (1.0f + __expf(-p0));
    float s1 = 1.0f / (1.0f + __expf(-p1));
    __hip_bfloat16 h0 = __float2bfloat16(s0);
    __hip_bfloat16 h1 = __float2bfloat16(s1);
    unsigned short* dst = ST + ((size_t)(b * NN + m)) * NN;
    dst[k0] = *reinterpret_cast<unsigned short*>(&h0);
    dst[k1] = *reinterpret_cast<unsigned short*>(&h1);
  }
}

// ---------------------------------------------------------------------------
// Kernel 5b (v2): E at masked entries. Block (m, b-half of 32).
//   LDS sfL[32][512] f32 (exactly 64 KB), XOR-swizzled: element e of row r
//   stored at e ^ ((r&15)<<1). Read as float2 -> banks 2-way (free, m136).
//   Lane = (q = lane>>5, b = lane&31): entry dot over k-half [q*256,+256):
//   64 uniform float4 Ve loads (32-lane broadcast) + 128 ds_read_b64 +
//   256 FMA, then shfl_xor(32) combines halves. No unpack in inner loop.
//   R12's k_E_col died on 16-useful-bytes-per-VMEM Ve reads; this fixes it.
// ---------------------------------------------------------------------------
__global__ __launch_bounds__(256) void k_E_col2(
    const unsigned short* __restrict__ ST, const float* __restrict__ Ve,
    const int* __restrict__ ccnt, const unsigned* __restrict__ colj,
    float* __restrict__ evals)
{
  int m  = blockIdx.x;   // 0..511
  int bh = blockIdx.y;   // 0..1 -> batches bh*32 .. bh*32+31

  __shared__ float sfL[32][512];   // 64 KB exactly

  int tid = threadIdx.x;
  int wv = tid >> 6, lane = tid & 63;

  // stage: row r (local batch), 512 bf16 -> f32, swizzled e ^ ((r&15)<<1)
  {
    int r = tid >> 3;            // 0..31
    int seg = tid & 7;           // 0..7 -> 64 elems each
    int swz = (r & 15) << 1;
    const unsigned* src = reinterpret_cast<const unsigned*>(
        ST + ((size_t)((bh * 32 + r) * NN + m)) * NN) + seg * 32;
    #pragma unroll
    for (int i = 0; i < 32; ++i) {
      unsigned u = src[i];
      int e = (seg * 64 + 2 * i) ^ swz;   // even ^ even -> even, float2-aligned
      *(float2*)&sfL[r][e] = make_float2(bflo(u), bfhi(u));
    }
  }
  __syncthreads();

  int cnt = ccnt[m];
  if (cnt > MAXNZ) cnt = MAXNZ;

  int q = lane >> 5, b = lane & 31;
  int swz = (b & 15) << 1;

  for (int e = wv; e < cnt; e += 4) {
    unsigned pk = colj[m * MAXNZ + e];
    int j = pk & 0xffff, slot = (int)(pk >> 16);
    const float4* vr = (const float4*)(Ve + (size_t)j * 512) + q * 64;
    const float* sb = sfL[b];
    int kb = q * 256;
    float a = 0.f;
    #pragma unroll 8
    for (int kk = 0; kk < 64; ++kk) {
      float4 v4 = vr[kk];
      int e0 = (kb + 4 * kk) ^ swz;
      float2 s0 = *(const float2*)&sb[e0];
      float2 s1 = *(const float2*)&sb[e0 ^ 2];
      a = fmaf(v4.x, s0.x, a);
      a = fmaf(v4.y, s0.y, a);
      a = fmaf(v4.z, s1.x, a);
      a = fmaf(v4.w, s1.y, a);
    }
    a += __shfl_xor(a, 32, 64);
    if (q == 0)
      evals[((size_t)((bh * 32 + b) * NN) + j) * MAXNZ + slot] = a;
  }
}

// ---------------------------------------------------------------------------
// Kernel 5 (fallback): fused product+sigmoid+E (R10 version)
// ---------------------------------------------------------------------------
__global__ __launch_bounds__(256) void k_product_E(
    const float* __restrict__ lhs, const float* __restrict__ rhsS,
    const float* __restrict__ beT, const float* __restrict__ Ve,
    const int* __restrict__ ccnt, const unsigned* __restrict__ colj,
    float* __restrict__ evals)
{
  int b  = blockIdx.x;
  int mc = blockIdx.y;

  __shared__ float lhsL[512 * 13];
  __shared__ float sL[4][512];
  __shared__ float rh[MCH * 12];

  int tid = threadIdx.x;
  const float* src = lhs + (size_t)b * 512 * 12;
  for (int i = tid; i < 6144; i += 256) {
    int k = i / 12, t = i - k * 12;
    lhsL[k * 13 + t] = src[i];
  }
  if (tid < MCH * 12) rh[tid] = rhsS[((size_t)b * 512 + mc * MCH) * 12 + tid];
  __syncthreads();

  int wave = tid >> 6, lane = tid & 63;
  int grp = lane >> 4, lg = lane & 15;

  for (int g = 0; g < MCH / 4; ++g) {
    if (g) __syncthreads();
    for (int i = tid; i < 4 * 512; i += 256) {
      int w = i >> 9, k = i & 511;
      int m = mc * MCH + g * 4 + w;
      float p = beT[m * 512 + k];
      const float* lr = &lhsL[k * 13];
      const float* rw = &rh[(g * 4 + w) * 12];
      #pragma unroll
      for (int t = 0; t < 12; ++t) p += lr[t] * rw[t];
      sL[w][k] = 1.0f / (1.0f + __expf(-p));
    }
    __syncthreads();

    int m = mc * MCH + g * 4 + wave;
    int cnt = ccnt[m];
    if (cnt > MAXNZ) cnt = MAXNZ;
    const float* sw = sL[wave];
    for (int e = grp; e < cnt; e += 4) {
      unsigned pk = colj[m * MAXNZ + e];
      int j = pk & 0xffff, slot = (int)(pk >> 16);
      const float* vr = Ve + (size_t)j * 512;
      float part = 0.f;
      #pragma unroll
      for (int kk = 0; kk < 32; ++kk)
        part = fmaf(vr[kk * 16 + lg], sw[kk * 16 + lg], part);
      #pragma unroll
      for (int off = 8; off; off >>= 1) part += __shfl_xor(part, off, 64);
      if (lg == 0) evals[((size_t)b * 512 + j) * MAXNZ + slot] = part;
    }
  }
}

// ---------------------------------------------------------------------------
// Kernel 6: masked softmax (unchanged)
// ---------------------------------------------------------------------------
__global__ __launch_bounds__(256) void k_softmax(
    const int* __restrict__ nnz, float* __restrict__ evals)
{
  int unit = blockIdx.x * 4 + (threadIdx.x >> 6);  // b*512 + j
  int lane = threadIdx.x & 63;
  int j = unit & 511;
  int cnt = nnz[j];
  float* ev = evals + (size_t)unit * MAXNZ;
  float v0 = lane < cnt        ? ev[lane]      : -__builtin_inff();
  float v1 = (lane + 64) < cnt ? ev[lane + 64] : -__builtin_inff();
  float mx = fmaxf(v0, v1);
  #pragma unroll
  for (int off = 32; off; off >>= 1) mx = fmaxf(mx, __shfl_xor(mx, off, 64));
  float e0 = lane < cnt        ? __expf(v0 - mx) : 0.f;
  float e1 = (lane + 64) < cnt ? __expf(v1 - mx) : 0.f;
  float s = wred_sum(e0 + e1);
  float inv = 1.0f / s;
  if (lane < cnt)        ev[lane]      = e0 * inv;
  if ((lane + 64) < cnt) ev[lane + 64] = e1 * inv;
}

// ---------------------------------------------------------------------------
// Kernel 7 (v10): wave per (b,j). xT imm-offset bf16 gather + f-tiled GEMM.
// ---------------------------------------------------------------------------
__global__ __launch_bounds__(256) void k_out10(
    const unsigned short* __restrict__ xT,
    const int* __restrict__ nnz, const int* __restrict__ cidx,
    const float* __restrict__ evals,
    const float* __restrict__ K, const float* __restrict__ bias,
    float* __restrict__ out)
{
  int tid = threadIdx.x;
  int wv = tid >> 6, lane = tid & 63;
  int bid = blockIdx.x;
  int sbid = (bid & 7) * 1024 + (bid >> 3);  // bijective on [0,8192)
  int unit = sbid * 4 + wv;                  // b*512 + j
  int b = unit >> 9, j = unit & 511;

  __shared__ float convL[4][12][64];
  __shared__ float valL[4][MAXNZ];
  __shared__ int   idxL[4][MAXNZ];

  int cnt = nnz[j];
  for (int s = lane; s < cnt; s += 64) {
    idxL[wv][s] = cidx[j * MAXNZ + s];
    valL[wv][s] = evals[(size_t)unit * MAXNZ + s];
  }

  float2 acc[6];
  #pragma unroll
  for (int i = 0; i < 6; ++i) acc[i] = make_float2(0.f, 0.f);

  const unsigned* xb = reinterpret_cast<const unsigned*>(
      xT + (size_t)b * NN * (TT * FF));

  int s = 0;
  for (; s + 1 < cnt; s += 2) {
    int   k0 = idxL[wv][s],     k1 = idxL[wv][s + 1];
    float v0 = valL[wv][s],     v1 = valL[wv][s + 1];
    const unsigned* p0 = xb + k0 * 384 + lane;
    const unsigned* p1 = xb + k1 * 384 + lane;
    unsigned a0 = p0[0],   a1 = p0[64],  a2 = p0[128],
             a3 = p0[192], a4 = p0[256], a5 = p0[320];
    unsigned c0 = p1[0],   c1 = p1[64],  c2 = p1[128],
             c3 = p1[192], c4 = p1[256], c5 = p1[320];
    acc[0].x = fmaf(v0, bflo(a0), acc[0].x); acc[0].y = fmaf(v0, bfhi(a0), acc[0].y);
    acc[1].x = fmaf(v0, bflo(a1), acc[1].x); acc[1].y = fmaf(v0, bfhi(a1), acc[1].y);
    acc[2].x = fmaf(v0, bflo(a2), acc[2].x); acc[2].y = fmaf(v0, bfhi(a2), acc[2].y);
    acc[3].x = fmaf(v0, bflo(a3), acc[3].x); acc[3].y = fmaf(v0, bfhi(a3), acc[3].y);
    acc[4].x = fmaf(v0, bflo(a4), acc[4].x); acc[4].y = fmaf(v0, bfhi(a4), acc[4].y);
    acc[5].x = fmaf(v0, bflo(a5), acc[5].x); acc[5].y = fmaf(v0, bfhi(a5), acc[5].y);
    acc[0].x = fmaf(v1, bflo(c0), acc[0].x); acc[0].y = fmaf(v1, bfhi(c0), acc[0].y);
    acc[1].x = fmaf(v1, bflo(c1), acc[1].x); acc[1].y = fmaf(v1, bfhi(c1), acc[1].y);
    acc[2].x = fmaf(v1, bflo(c2), acc[2].x); acc[2].y = fmaf(v1, bfhi(c2), acc[2].y);
    acc[3].x = fmaf(v1, bflo(c3), acc[3].x); acc[3].y = fmaf(v1, bfhi(c3), acc[3].y);
    acc[4].x = fmaf(v1, bflo(c4), acc[4].x); acc[4].y = fmaf(v1, bfhi(c4), acc[4].y);
    acc[5].x = fmaf(v1, bflo(c5), acc[5].x); acc[5].y = fmaf(v1, bfhi(c5), acc[5].y);
  }
  if (s < cnt) {
    int   k0 = idxL[wv][s];
    float v0 = valL[wv][s];
    const unsigned* p0 = xb + k0 * 384 + lane;
    unsigned a0 = p0[0],   a1 = p0[64],  a2 = p0[128],
             a3 = p0[192], a4 = p0[256], a5 = p0[320];
    acc[0].x = fmaf(v0, bflo(a0), acc[0].x); acc[0].y = fmaf(v0, bfhi(a0), acc[0].y);
    acc[1].x = fmaf(v0, bflo(a1), acc[1].x); acc[1].y = fmaf(v0, bfhi(a1), acc[1].y);
    acc[2].x = fmaf(v0, bflo(a2), acc[2].x); acc[2].y = fmaf(v0, bfhi(a2), acc[2].y);
    acc[3].x = fmaf(v0, bflo(a3), acc[3].x); acc[3].y = fmaf(v0, bfhi(a3), acc[3].y);
    acc[4].x = fmaf(v0, bflo(a4), acc[4].x); acc[4].y = fmaf(v0, bfhi(a4), acc[4].y);
    acc[5].x = fmaf(v0, bflo(a5), acc[5].x); acc[5].y = fmaf(v0, bfhi(a5), acc[5].y);
  }

  int half = lane >> 5, fl = lane & 31;
  #pragma unroll
  for (int i = 0; i < 6; ++i)
    *(float2*)&convL[wv][2 * i + half][fl * 2] = acc[i];

  float bs = bias[lane];
  float o[12];
  #pragma unroll
  for (int t = 0; t < 12; ++t) o[t] = bs;

  __syncthreads();

  #pragma unroll
  for (int ft = 0; ft < 4; ++ft) {
    float kc[16];
    #pragma unroll
    for (int i = 0; i < 16; ++i) kc[i] = K[(ft * 16 + i) * 64 + lane];
    #pragma unroll
    for (int t = 0; t < 12; ++t) {
      const float4* cv = (const float4*)&convL[wv][t][ft * 16];
      float4 c0 = cv[0], c1 = cv[1], c2 = cv[2], c3 = cv[3];
      o[t] += c0.x * kc[0]  + c0.y * kc[1]  + c0.z * kc[2]  + c0.w * kc[3]
            + c1.x * kc[4]  + c1.y * kc[5]  + c1.z * kc[6]  + c1.w * kc[7]
            + c2.x * kc[8]  + c2.y * kc[9]  + c2.z * kc[10] + c2.w * kc[11]
            + c3.x * kc[12] + c3.y * kc[13] + c3.z * kc[14] + c3.w * kc[15];
    }
  }

  #pragma unroll
  for (int t = 0; t < 12; ++t)
    out[((size_t)(b * TT + t) * NN + j) * UU + lane] = o[t];
}

// ---------------------------------------------------------------------------
// Kernel 7 fallback (fp32 scalar gather + f-tiled phase B) — if ws small
// ---------------------------------------------------------------------------
__global__ __launch_bounds__(256) void k_out3f(
    const float* __restrict__ x,
    const int* __restrict__ nnz, const int* __restrict__ cidx,
    const float* __restrict__ evals,
    const float* __restrict__ K, const float* __restrict__ bias,
    float* __restrict__ out)
{
  int wv = threadIdx.x >> 6, lane = threadIdx.x & 63;
  int bid = blockIdx.x;
  int sbid = (bid & 7) * 1024 + (bid >> 3);
  int unit = sbid * 4 + wv;
  int b = unit >> 9, j = unit & 511;

  __shared__ float convL[4][12][64];
  __shared__ float valL[4][MAXNZ];
  __shared__ int   idxL[4][MAXNZ];

  int cnt = nnz[j];
  for (int s = lane; s < cnt; s += 64) {
    idxL[wv][s] = cidx[j * MAXNZ + s];
    valL[wv][s] = evals[(size_t)unit * MAXNZ + s];
  }

  float acc[12];
  #pragma unroll
  for (int t = 0; t < 12; ++t) acc[t] = 0.f;

  const float* xb = x + (size_t)b * TT * NN * FF + lane;
  for (int s = 0; s < cnt; ++s) {
    float v = valL[wv][s];
    const float* xk = xb + (size_t)idxL[wv][s] * FF;
    #pragma unroll
    for (int t = 0; t < 12; ++t)
      acc[t] = fmaf(v, xk[(size_t)t * NN * FF], acc[t]);
  }
  #pragma unroll
  for (int t = 0; t < 12; ++t) convL[wv][t][lane] = acc[t];

  float bs = bias[lane];
  float o[12];
  #pragma unroll
  for (int t = 0; t < 12; ++t) o[t] = bs;
  __syncthreads();

  #pragma unroll
  for (int ft = 0; ft < 4; ++ft) {
    float kc[16];
    #pragma unroll
    for (int i = 0; i < 16; ++i) kc[i] = K[(ft * 16 + i) * 64 + lane];
    #pragma unroll
    for (int t = 0; t < 12; ++t) {
      const float4* cv = (const float4*)&convL[wv][t][ft * 16];
      float4 c0 = cv[0], c1 = cv[1], c2 = cv[2], c3 = cv[3];
      o[t] += c0.x * kc[0]  + c0.y * kc[1]  + c0.z * kc[2]  + c0.w * kc[3]
            + c1.x * kc[4]  + c1.y * kc[5]  + c1.z * kc[6]  + c1.w * kc[7]
            + c2.x * kc[8]  + c2.y * kc[9]  + c2.z * kc[10] + c2.w * kc[11]
            + c3.x * kc[12] + c3.y * kc[13] + c3.z * kc[14] + c3.w * kc[15];
    }
  }

  #pragma unroll
  for (int t = 0; t < 12; ++t)
    out[((size_t)(b * TT + t) * NN + j) * UU + lane] = o[t];
}

// ---------------------------------------------------------------------------
extern "C" void kernel_launch(void* const* d_in, const int* in_sizes, int n_in,
                              void* d_out, int out_size, void* d_ws, size_t ws_size,
                              hipStream_t stream)
{
  const float* x    = (const float*)d_in[0];  // (B,T,N,F)
  const float* A    = (const float*)d_in[1];  // (N,N)
  const float* W1   = (const float*)d_in[2];  // (T,1)
  const float* W2   = (const float*)d_in[3];  // (F,T)
  const float* W3   = (const float*)d_in[4];  // (F,1)
  const float* Ve   = (const float*)d_in[5];  // (N,N)
  const float* be   = (const float*)d_in[6];  // (N,N)
  const float* K    = (const float*)d_in[7];  // (F,U)
  const float* bias = (const float*)d_in[8];  // (U,)
  float* out = (float*)d_out;

  char* ws = (char*)d_ws;
  float* lhs   = (float*)ws + OF_LHS;
  float* rhsS  = (float*)ws + OF_RHS;
  float* beT   = (float*)ws + OF_BET;
  float* evals = (float*)ws + OF_EVALS;
  int*      nnz  = (int*)(ws + OB_NNZ);
  int*      cidx = (int*)(ws + OB_CIDX);
  int*      ccnt = (int*)(ws + OB_CCNT);
  unsigned* colj = (unsigned*)(ws + OB_COLJ);
  unsigned short* xT = (unsigned short*)(ws + OB_XT);
  unsigned short* ST = (unsigned short*)(ws + OB_ST);

  const bool use_xt    = ws_size >= OB_XT + XT_BYTES;
  const bool use_fastE = ws_size >= OB_ST + ST_BYTES;

  hipMemsetAsync(ccnt, 0, NN * sizeof(int), stream);

  // 1. lhs / rhs (+ transposed bf16 copy of x)
  k_lhs_rhs<<<dim3(BB * NN / 4), dim3(256), 0, stream>>>(
      x, W1, W2, W3, lhs, rhsS, use_xt ? xT : nullptr);
  // 2. transpose be
  k_transpose<<<dim3(NN * NN / 256), dim3(256), 0, stream>>>(be, beT);
  // 3. row index lists
  k_build_idx<<<dim3(NN), dim3(64), 0, stream>>>(A, nnz, cidx);
  // 4. column lists
  k_build_col<<<dim3(NN), dim3(64), 0, stream>>>(nnz, cidx, ccnt, colj);
  // 5. product + sigmoid + masked E
  if (use_fastE) {
    k_sigmoid<<<dim3(BB, NN / 16), dim3(256), 0, stream>>>(lhs, rhsS, beT, ST);
    k_E_col2<<<dim3(NN, 2), dim3(256), 0, stream>>>(ST, Ve, ccnt, colj, evals);
  } else {
    k_product_E<<<dim3(BB, NN / MCH), dim3(256), 0, stream>>>(lhs, rhsS, beT, Ve, ccnt, colj, evals);
  }
  // 6. softmax over slots
  k_softmax<<<dim3(BB * NN / 4), dim3(256), 0, stream>>>(nnz, evals);
  // 7. sparse conv + f-tiled output GEMM
  if (use_xt)
    k_out10<<<dim3(BB * NN / 4), dim3(256), 0, stream>>>(xT, nnz, cidx, evals, K, bias, out);
  else
    k_out3f<<<dim3(BB * NN / 4), dim3(256), 0, stream>>>(x, nnz, cidx, evals, K, bias, out);
}

// Round 14
// 260.033 us; speedup vs baseline: 1.0819x; 1.0396x over previous
//
#include <hip/hip_runtime.h>
#include <hip/hip_bf16.h>
#include <cstdint>

// Problem constants
constexpr int BB = 64;    // batch
constexpr int TT = 12;    // time
constexpr int NN = 512;   // nodes
constexpr int FF = 64;    // features
constexpr int UU = 64;    // units
constexpr int MAXNZ = 128;
constexpr int MCH = 16;   // m-columns per k_product_E block

// ---------------------------------------------------------------------------
// Workspace layout (bytes):
//   floats: lhs 0 / rhs 393216f / beT 786432f / evals 1048576f
//   ints:   nnz 20971520 / cidx 20973568 / ccnt 21235712 / colj 21237760
//   xT (B,N,T,F) bf16 : 21516288, 50331648 B
// ---------------------------------------------------------------------------
constexpr size_t OF_LHS   = 0;
constexpr size_t OF_RHS   = 393216;
constexpr size_t OF_BET   = 786432;
constexpr size_t OF_EVALS = 1048576;
constexpr size_t OB_NNZ   = 20971520;
constexpr size_t OB_CIDX  = 20973568;
constexpr size_t OB_CCNT  = 21235712;
constexpr size_t OB_COLJ  = 21237760;
constexpr size_t OB_XT    = 21516288;
constexpr size_t XT_BYTES = (size_t)BB * NN * TT * FF * 2;  // 50331648

__device__ __forceinline__ float wred_sum(float v) {
  #pragma unroll
  for (int off = 32; off; off >>= 1) v += __shfl_xor(v, off, 64);
  return v;
}

__device__ __forceinline__ float bflo(unsigned u) {
  return __uint_as_float(u << 16);
}
__device__ __forceinline__ float bfhi(unsigned u) {
  return __uint_as_float(u & 0xFFFF0000u);
}

// ---------------------------------------------------------------------------
// Kernel 1: lhs/rhs reductions; also writes xT[b][n][t][f] bf16
// ---------------------------------------------------------------------------
__global__ __launch_bounds__(256) void k_lhs_rhs(
    const float* __restrict__ x, const float* __restrict__ W1,
    const float* __restrict__ W2, const float* __restrict__ W3,
    float* __restrict__ lhs, float* __restrict__ rhsS,
    unsigned short* __restrict__ xT)   // may be null
{
  int unit = blockIdx.x * 4 + (threadIdx.x >> 6);   // b*512 + n
  int lane = threadIdx.x & 63;
  int b = unit >> 9, n = unit & 511;

  const float* xb = x + ((size_t)b * TT * NN + n) * FF + lane;
  float xv[12];
  #pragma unroll
  for (int t = 0; t < 12; ++t) xv[t] = xb[(size_t)t * NN * FF];

  if (xT) {
    unsigned short* xo = xT + (size_t)unit * (TT * FF) + lane;
    #pragma unroll
    for (int t = 0; t < 12; ++t) {
      __hip_bfloat16 h = __float2bfloat16(xv[t]);   // RTNE
      xo[t * FF] = *reinterpret_cast<unsigned short*>(&h);
    }
  }

  float r1 = 0.f;
  #pragma unroll
  for (int t = 0; t < 12; ++t) r1 += xv[t] * W1[t];

  float w3 = W3[lane];

  float myl = 0.f, myr = 0.f;
  #pragma unroll
  for (int t = 0; t < 12; ++t) {
    float a = r1 * W2[lane * 12 + t];
    float c = xv[t] * w3;
    a = wred_sum(a);
    c = wred_sum(c);
    if (lane == t) { myl = a; myr = c; }
  }
  if (lane < 12) {
    lhs[(size_t)unit * 12 + lane]  = myl;
    rhsS[(size_t)unit * 12 + lane] = myr;
  }
}

// ---------------------------------------------------------------------------
// Kernel 2: beT[m,k] = be[k,m]
// ---------------------------------------------------------------------------
__global__ __launch_bounds__(256) void k_transpose(
    const float* __restrict__ be, float* __restrict__ beT)
{
  int i = blockIdx.x * 256 + threadIdx.x;  // 262144 total
  int k = i >> 9, m = i & 511;
  beT[m * 512 + k] = be[i];
}

// ---------------------------------------------------------------------------
// Kernel 3: row-wise compaction of mask A (deterministic, ordered by m)
// ---------------------------------------------------------------------------
__global__ void k_build_idx(const float* __restrict__ A,
                            int* __restrict__ nnz, int* __restrict__ cidx)
{
  int j = blockIdx.x;
  int lane = threadIdx.x;  // 64 threads
  unsigned long long lt = (1ull << lane) - 1ull;
  int base = 0;
  for (int c = 0; c < 8; ++c) {
    int m = c * 64 + lane;
    bool p = A[(size_t)j * 512 + m] > 0.5f;
    unsigned long long mask = __ballot(p);
    int pos = base + __popcll(mask & lt);
    if (p && pos < MAXNZ) cidx[j * MAXNZ + pos] = m;
    base += __popcll(mask);
  }
  if (lane == 0) nnz[j] = base > MAXNZ ? MAXNZ : base;
}

// ---------------------------------------------------------------------------
// Kernel 4: column lists
// ---------------------------------------------------------------------------
__global__ void k_build_col(const int* __restrict__ nnz, const int* __restrict__ cidx,
                            int* __restrict__ ccnt, unsigned* __restrict__ colj)
{
  int j = blockIdx.x;
  int lane = threadIdx.x;
  int cnt = nnz[j];
  for (int s = lane; s < cnt; s += 64) {
    int m = cidx[j * MAXNZ + s];
    int pos = atomicAdd(&ccnt[m], 1);
    if (pos < MAXNZ) colj[m * MAXNZ + pos] = (unsigned)j | ((unsigned)s << 16);
  }
}

// ---------------------------------------------------------------------------
// Kernel 5 (fused, R11-proven ~105us): product + sigmoid + masked E
// ---------------------------------------------------------------------------
__global__ __launch_bounds__(256) void k_product_E(
    const float* __restrict__ lhs, const float* __restrict__ rhsS,
    const float* __restrict__ beT, const float* __restrict__ Ve,
    const int* __restrict__ ccnt, const unsigned* __restrict__ colj,
    float* __restrict__ evals)
{
  int b  = blockIdx.x;
  int mc = blockIdx.y;

  __shared__ float lhsL[512 * 13];
  __shared__ float sL[4][512];
  __shared__ float rh[MCH * 12];

  int tid = threadIdx.x;
  const float* src = lhs + (size_t)b * 512 * 12;
  for (int i = tid; i < 6144; i += 256) {
    int k = i / 12, t = i - k * 12;
    lhsL[k * 13 + t] = src[i];
  }
  if (tid < MCH * 12) rh[tid] = rhsS[((size_t)b * 512 + mc * MCH) * 12 + tid];
  __syncthreads();

  int wave = tid >> 6, lane = tid & 63;
  int grp = lane >> 4, lg = lane & 15;

  for (int g = 0; g < MCH / 4; ++g) {
    if (g) __syncthreads();
    for (int i = tid; i < 4 * 512; i += 256) {
      int w = i >> 9, k = i & 511;
      int m = mc * MCH + g * 4 + w;
      float p = beT[m * 512 + k];
      const float* lr = &lhsL[k * 13];
      const float* rw = &rh[(g * 4 + w) * 12];
      #pragma unroll
      for (int t = 0; t < 12; ++t) p += lr[t] * rw[t];
      sL[w][k] = 1.0f / (1.0f + __expf(-p));
    }
    __syncthreads();

    int m = mc * MCH + g * 4 + wave;
    int cnt = ccnt[m];
    if (cnt > MAXNZ) cnt = MAXNZ;
    const float* sw = sL[wave];
    for (int e = grp; e < cnt; e += 4) {
      unsigned pk = colj[m * MAXNZ + e];
      int j = pk & 0xffff, slot = (int)(pk >> 16);
      const float* vr = Ve + (size_t)j * 512;
      float part = 0.f;
      #pragma unroll
      for (int kk = 0; kk < 32; ++kk)
        part = fmaf(vr[kk * 16 + lg], sw[kk * 16 + lg], part);
      #pragma unroll
      for (int off = 8; off; off >>= 1) part += __shfl_xor(part, off, 64);
      if (lg == 0) evals[((size_t)b * 512 + j) * MAXNZ + slot] = part;
    }
  }
}

// ---------------------------------------------------------------------------
// Kernel 6 (v11): wave per (b,j). xT imm-offset bf16 gather + FUSED softmax
//   + f-tiled GEMM with explicit fmaf chains.
//   R13 evidence: `o += a*b + c*d + ...` is a sum tree (16 mul + 16 add);
//   without fast-math the compiler can't reassociate -> phase B was 2x VALU.
//   Explicit fmaf halves it. Softmax fused: the wave already holds its
//   slot values in valL; ~25 VALU replaces a dispatch + evals round trip.
// XCD swizzle: grid = 8192, sbid = (bid&7)*1024 + (bid>>3) bijective.
// ---------------------------------------------------------------------------
__global__ __launch_bounds__(256) void k_out11(
    const unsigned short* __restrict__ xT,
    const int* __restrict__ nnz, const int* __restrict__ cidx,
    const float* __restrict__ evals,
    const float* __restrict__ K, const float* __restrict__ bias,
    float* __restrict__ out)
{
  int tid = threadIdx.x;
  int wv = tid >> 6, lane = tid & 63;
  int bid = blockIdx.x;
  int sbid = (bid & 7) * 1024 + (bid >> 3);  // bijective on [0,8192)
  int unit = sbid * 4 + wv;                  // b*512 + j
  int b = unit >> 9, j = unit & 511;

  __shared__ float convL[4][12][64];
  __shared__ float valL[4][MAXNZ];
  __shared__ int   idxL[4][MAXNZ];

  int cnt = nnz[j];
  for (int s = lane; s < cnt; s += 64) {
    idxL[wv][s] = cidx[j * MAXNZ + s];
    valL[wv][s] = evals[(size_t)unit * MAXNZ + s];
  }
  // ---- fused masked softmax over this wave's slots (wave-local LDS) ----
  {
    float v0 = lane < cnt        ? valL[wv][lane]      : -__builtin_inff();
    float v1 = (lane + 64) < cnt ? valL[wv][lane + 64] : -__builtin_inff();
    float mx = fmaxf(v0, v1);
    #pragma unroll
    for (int off = 32; off; off >>= 1) mx = fmaxf(mx, __shfl_xor(mx, off, 64));
    float e0 = lane < cnt        ? __expf(v0 - mx) : 0.f;
    float e1 = (lane + 64) < cnt ? __expf(v1 - mx) : 0.f;
    float ssum = wred_sum(e0 + e1);
    float inv = 1.0f / ssum;
    if (lane < cnt)        valL[wv][lane]      = e0 * inv;
    if ((lane + 64) < cnt) valL[wv][lane + 64] = e1 * inv;
  }

  float2 acc[6];
  #pragma unroll
  for (int i = 0; i < 6; ++i) acc[i] = make_float2(0.f, 0.f);

  const unsigned* xb = reinterpret_cast<const unsigned*>(
      xT + (size_t)b * NN * (TT * FF));

  int s = 0;
  for (; s + 1 < cnt; s += 2) {
    int   k0 = idxL[wv][s],     k1 = idxL[wv][s + 1];
    float v0 = valL[wv][s],     v1 = valL[wv][s + 1];
    const unsigned* p0 = xb + k0 * 384 + lane;
    const unsigned* p1 = xb + k1 * 384 + lane;
    unsigned a0 = p0[0],   a1 = p0[64],  a2 = p0[128],
             a3 = p0[192], a4 = p0[256], a5 = p0[320];
    unsigned c0 = p1[0],   c1 = p1[64],  c2 = p1[128],
             c3 = p1[192], c4 = p1[256], c5 = p1[320];
    acc[0].x = fmaf(v0, bflo(a0), acc[0].x); acc[0].y = fmaf(v0, bfhi(a0), acc[0].y);
    acc[1].x = fmaf(v0, bflo(a1), acc[1].x); acc[1].y = fmaf(v0, bfhi(a1), acc[1].y);
    acc[2].x = fmaf(v0, bflo(a2), acc[2].x); acc[2].y = fmaf(v0, bfhi(a2), acc[2].y);
    acc[3].x = fmaf(v0, bflo(a3), acc[3].x); acc[3].y = fmaf(v0, bfhi(a3), acc[3].y);
    acc[4].x = fmaf(v0, bflo(a4), acc[4].x); acc[4].y = fmaf(v0, bfhi(a4), acc[4].y);
    acc[5].x = fmaf(v0, bflo(a5), acc[5].x); acc[5].y = fmaf(v0, bfhi(a5), acc[5].y);
    acc[0].x = fmaf(v1, bflo(c0), acc[0].x); acc[0].y = fmaf(v1, bfhi(c0), acc[0].y);
    acc[1].x = fmaf(v1, bflo(c1), acc[1].x); acc[1].y = fmaf(v1, bfhi(c1), acc[1].y);
    acc[2].x = fmaf(v1, bflo(c2), acc[2].x); acc[2].y = fmaf(v1, bfhi(c2), acc[2].y);
    acc[3].x = fmaf(v1, bflo(c3), acc[3].x); acc[3].y = fmaf(v1, bfhi(c3), acc[3].y);
    acc[4].x = fmaf(v1, bflo(c4), acc[4].x); acc[4].y = fmaf(v1, bfhi(c4), acc[4].y);
    acc[5].x = fmaf(v1, bflo(c5), acc[5].x); acc[5].y = fmaf(v1, bfhi(c5), acc[5].y);
  }
  if (s < cnt) {
    int   k0 = idxL[wv][s];
    float v0 = valL[wv][s];
    const unsigned* p0 = xb + k0 * 384 + lane;
    unsigned a0 = p0[0],   a1 = p0[64],  a2 = p0[128],
             a3 = p0[192], a4 = p0[256], a5 = p0[320];
    acc[0].x = fmaf(v0, bflo(a0), acc[0].x); acc[0].y = fmaf(v0, bfhi(a0), acc[0].y);
    acc[1].x = fmaf(v0, bflo(a1), acc[1].x); acc[1].y = fmaf(v0, bfhi(a1), acc[1].y);
    acc[2].x = fmaf(v0, bflo(a2), acc[2].x); acc[2].y = fmaf(v0, bfhi(a2), acc[2].y);
    acc[3].x = fmaf(v0, bflo(a3), acc[3].x); acc[3].y = fmaf(v0, bfhi(a3), acc[3].y);
    acc[4].x = fmaf(v0, bflo(a4), acc[4].x); acc[4].y = fmaf(v0, bfhi(a4), acc[4].y);
    acc[5].x = fmaf(v0, bflo(a5), acc[5].x); acc[5].y = fmaf(v0, bfhi(a5), acc[5].y);
  }

  int half = lane >> 5, fl = lane & 31;
  #pragma unroll
  for (int i = 0; i < 6; ++i)
    *(float2*)&convL[wv][2 * i + half][fl * 2] = acc[i];

  float bs = bias[lane];
  float o[12];
  #pragma unroll
  for (int t = 0; t < 12; ++t) o[t] = bs;

  __syncthreads();

  #pragma unroll
  for (int ft = 0; ft < 4; ++ft) {
    float kc[16];
    #pragma unroll
    for (int i = 0; i < 16; ++i) kc[i] = K[(ft * 16 + i) * 64 + lane];
    #pragma unroll
    for (int t = 0; t < 12; ++t) {
      const float4* cv = (const float4*)&convL[wv][t][ft * 16];
      float4 c0 = cv[0], c1 = cv[1], c2 = cv[2], c3 = cv[3];
      float o_ = o[t];
      o_ = fmaf(c0.x, kc[0],  o_); o_ = fmaf(c0.y, kc[1],  o_);
      o_ = fmaf(c0.z, kc[2],  o_); o_ = fmaf(c0.w, kc[3],  o_);
      o_ = fmaf(c1.x, kc[4],  o_); o_ = fmaf(c1.y, kc[5],  o_);
      o_ = fmaf(c1.z, kc[6],  o_); o_ = fmaf(c1.w, kc[7],  o_);
      o_ = fmaf(c2.x, kc[8],  o_); o_ = fmaf(c2.y, kc[9],  o_);
      o_ = fmaf(c2.z, kc[10], o_); o_ = fmaf(c2.w, kc[11], o_);
      o_ = fmaf(c3.x, kc[12], o_); o_ = fmaf(c3.y, kc[13], o_);
      o_ = fmaf(c3.z, kc[14], o_); o_ = fmaf(c3.w, kc[15], o_);
      o[t] = o_;
    }
  }

  #pragma unroll
  for (int t = 0; t < 12; ++t)
    out[((size_t)(b * TT + t) * NN + j) * UU + lane] = o[t];
}

// ---------------------------------------------------------------------------
// Kernel 6 fallback (fp32 scalar gather + fused softmax + fmaf phase B)
// ---------------------------------------------------------------------------
__global__ __launch_bounds__(256) void k_out3f(
    const float* __restrict__ x,
    const int* __restrict__ nnz, const int* __restrict__ cidx,
    const float* __restrict__ evals,
    const float* __restrict__ K, const float* __restrict__ bias,
    float* __restrict__ out)
{
  int wv = threadIdx.x >> 6, lane = threadIdx.x & 63;
  int bid = blockIdx.x;
  int sbid = (bid & 7) * 1024 + (bid >> 3);
  int unit = sbid * 4 + wv;
  int b = unit >> 9, j = unit & 511;

  __shared__ float convL[4][12][64];
  __shared__ float valL[4][MAXNZ];
  __shared__ int   idxL[4][MAXNZ];

  int cnt = nnz[j];
  for (int s = lane; s < cnt; s += 64) {
    idxL[wv][s] = cidx[j * MAXNZ + s];
    valL[wv][s] = evals[(size_t)unit * MAXNZ + s];
  }
  {
    float v0 = lane < cnt        ? valL[wv][lane]      : -__builtin_inff();
    float v1 = (lane + 64) < cnt ? valL[wv][lane + 64] : -__builtin_inff();
    float mx = fmaxf(v0, v1);
    #pragma unroll
    for (int off = 32; off; off >>= 1) mx = fmaxf(mx, __shfl_xor(mx, off, 64));
    float e0 = lane < cnt        ? __expf(v0 - mx) : 0.f;
    float e1 = (lane + 64) < cnt ? __expf(v1 - mx) : 0.f;
    float ssum = wred_sum(e0 + e1);
    float inv = 1.0f / ssum;
    if (lane < cnt)        valL[wv][lane]      = e0 * inv;
    if ((lane + 64) < cnt) valL[wv][lane + 64] = e1 * inv;
  }

  float acc[12];
  #pragma unroll
  for (int t = 0; t < 12; ++t) acc[t] = 0.f;

  const float* xb = x + (size_t)b * TT * NN * FF + lane;
  for (int s = 0; s < cnt; ++s) {
    float v = valL[wv][s];
    const float* xk = xb + (size_t)idxL[wv][s] * FF;
    #pragma unroll
    for (int t = 0; t < 12; ++t)
      acc[t] = fmaf(v, xk[(size_t)t * NN * FF], acc[t]);
  }
  #pragma unroll
  for (int t = 0; t < 12; ++t) convL[wv][t][lane] = acc[t];

  float bs = bias[lane];
  float o[12];
  #pragma unroll
  for (int t = 0; t < 12; ++t) o[t] = bs;
  __syncthreads();

  #pragma unroll
  for (int ft = 0; ft < 4; ++ft) {
    float kc[16];
    #pragma unroll
    for (int i = 0; i < 16; ++i) kc[i] = K[(ft * 16 + i) * 64 + lane];
    #pragma unroll
    for (int t = 0; t < 12; ++t) {
      const float4* cv = (const float4*)&convL[wv][t][ft * 16];
      float4 c0 = cv[0], c1 = cv[1], c2 = cv[2], c3 = cv[3];
      float o_ = o[t];
      o_ = fmaf(c0.x, kc[0],  o_); o_ = fmaf(c0.y, kc[1],  o_);
      o_ = fmaf(c0.z, kc[2],  o_); o_ = fmaf(c0.w, kc[3],  o_);
      o_ = fmaf(c1.x, kc[4],  o_); o_ = fmaf(c1.y, kc[5],  o_);
      o_ = fmaf(c1.z, kc[6],  o_); o_ = fmaf(c1.w, kc[7],  o_);
      o_ = fmaf(c2.x, kc[8],  o_); o_ = fmaf(c2.y, kc[9],  o_);
      o_ = fmaf(c2.z, kc[10], o_); o_ = fmaf(c2.w, kc[11], o_);
      o_ = fmaf(c3.x, kc[12], o_); o_ = fmaf(c3.y, kc[13], o_);
      o_ = fmaf(c3.z, kc[14], o_); o_ = fmaf(c3.w, kc[15], o_);
      o[t] = o_;
    }
  }

  #pragma unroll
  for (int t = 0; t < 12; ++t)
    out[((size_t)(b * TT + t) * NN + j) * UU + lane] = o[t];
}

// ---------------------------------------------------------------------------
extern "C" void kernel_launch(void* const* d_in, const int* in_sizes, int n_in,
                              void* d_out, int out_size, void* d_ws, size_t ws_size,
                              hipStream_t stream)
{
  const float* x    = (const float*)d_in[0];  // (B,T,N,F)
  const float* A    = (const float*)d_in[1];  // (N,N)
  const float* W1   = (const float*)d_in[2];  // (T,1)
  const float* W2   = (const float*)d_in[3];  // (F,T)
  const float* W3   = (const float*)d_in[4];  // (F,1)
  const float* Ve   = (const float*)d_in[5];  // (N,N)
  const float* be   = (const float*)d_in[6];  // (N,N)
  const float* K    = (const float*)d_in[7];  // (F,U)
  const float* bias = (const float*)d_in[8];  // (U,)
  float* out = (float*)d_out;

  char* ws = (char*)d_ws;
  float* lhs   = (float*)ws + OF_LHS;
  float* rhsS  = (float*)ws + OF_RHS;
  float* beT   = (float*)ws + OF_BET;
  float* evals = (float*)ws + OF_EVALS;
  int*      nnz  = (int*)(ws + OB_NNZ);
  int*      cidx = (int*)(ws + OB_CIDX);
  int*      ccnt = (int*)(ws + OB_CCNT);
  unsigned* colj = (unsigned*)(ws + OB_COLJ);
  unsigned short* xT = (unsigned short*)(ws + OB_XT);

  const bool use_xt = ws_size >= OB_XT + XT_BYTES;

  hipMemsetAsync(ccnt, 0, NN * sizeof(int), stream);

  // 1. lhs / rhs (+ transposed bf16 copy of x)
  k_lhs_rhs<<<dim3(BB * NN / 4), dim3(256), 0, stream>>>(
      x, W1, W2, W3, lhs, rhsS, use_xt ? xT : nullptr);
  // 2. transpose be
  k_transpose<<<dim3(NN * NN / 256), dim3(256), 0, stream>>>(be, beT);
  // 3. row index lists
  k_build_idx<<<dim3(NN), dim3(64), 0, stream>>>(A, nnz, cidx);
  // 4. column lists
  k_build_col<<<dim3(NN), dim3(64), 0, stream>>>(nnz, cidx, ccnt, colj);
  // 5. product + sigmoid + masked E (fused)
  k_product_E<<<dim3(BB, NN / MCH), dim3(256), 0, stream>>>(lhs, rhsS, beT, Ve, ccnt, colj, evals);
  // 6. sparse conv + fused softmax + fmaf-chain output GEMM
  if (use_xt)
    k_out11<<<dim3(BB * NN / 4), dim3(256), 0, stream>>>(xT, nnz, cidx, evals, K, bias, out);
  else
    k_out3f<<<dim3(BB * NN / 4), dim3(256), 0, stream>>>(x, nnz, cidx, evals, K, bias, out);
}

// Round 15
// 243.871 us; speedup vs baseline: 1.1536x; 1.0663x over previous
//
#include <hip/hip_runtime.h>
#include <hip/hip_bf16.h>
#include <cstdint>

// Problem constants
constexpr int BB = 64;    // batch
constexpr int TT = 12;    // time
constexpr int NN = 512;   // nodes
constexpr int FF = 64;    // features
constexpr int UU = 64;    // units
constexpr int MAXNZ = 128;

// ---------------------------------------------------------------------------
// Workspace layout (bytes):
//   floats: lhs 0 / rhs 393216f / beT 786432f / evals 1048576f
//   ints:   nnz 20971520 / cidx 20973568 / ccnt 21235712 / colj 21237760
//   xT (B,N,T,F) bf16 : 21516288, 50331648 B
// ---------------------------------------------------------------------------
constexpr size_t OF_LHS   = 0;
constexpr size_t OF_RHS   = 393216;
constexpr size_t OF_BET   = 786432;
constexpr size_t OF_EVALS = 1048576;
constexpr size_t OB_NNZ   = 20971520;
constexpr size_t OB_CIDX  = 20973568;
constexpr size_t OB_CCNT  = 21235712;
constexpr size_t OB_COLJ  = 21237760;
constexpr size_t OB_XT    = 21516288;
constexpr size_t XT_BYTES = (size_t)BB * NN * TT * FF * 2;  // 50331648

__device__ __forceinline__ float wred_sum(float v) {
  #pragma unroll
  for (int off = 32; off; off >>= 1) v += __shfl_xor(v, off, 64);
  return v;
}

__device__ __forceinline__ float bflo(unsigned u) {
  return __uint_as_float(u << 16);
}
__device__ __forceinline__ float bfhi(unsigned u) {
  return __uint_as_float(u & 0xFFFF0000u);
}

// ---------------------------------------------------------------------------
// Kernel 1: lhs/rhs reductions; also writes xT[b][n][t][f] bf16
// ---------------------------------------------------------------------------
__global__ __launch_bounds__(256) void k_lhs_rhs(
    const float* __restrict__ x, const float* __restrict__ W1,
    const float* __restrict__ W2, const float* __restrict__ W3,
    float* __restrict__ lhs, float* __restrict__ rhsS,
    unsigned short* __restrict__ xT)   // may be null
{
  int unit = blockIdx.x * 4 + (threadIdx.x >> 6);   // b*512 + n
  int lane = threadIdx.x & 63;
  int b = unit >> 9, n = unit & 511;

  const float* xb = x + ((size_t)b * TT * NN + n) * FF + lane;
  float xv[12];
  #pragma unroll
  for (int t = 0; t < 12; ++t) xv[t] = xb[(size_t)t * NN * FF];

  if (xT) {
    unsigned short* xo = xT + (size_t)unit * (TT * FF) + lane;
    #pragma unroll
    for (int t = 0; t < 12; ++t) {
      __hip_bfloat16 h = __float2bfloat16(xv[t]);   // RTNE
      xo[t * FF] = *reinterpret_cast<unsigned short*>(&h);
    }
  }

  float r1 = 0.f;
  #pragma unroll
  for (int t = 0; t < 12; ++t) r1 += xv[t] * W1[t];

  float w3 = W3[lane];

  float myl = 0.f, myr = 0.f;
  #pragma unroll
  for (int t = 0; t < 12; ++t) {
    float a = r1 * W2[lane * 12 + t];
    float c = xv[t] * w3;
    a = wred_sum(a);
    c = wred_sum(c);
    if (lane == t) { myl = a; myr = c; }
  }
  if (lane < 12) {
    lhs[(size_t)unit * 12 + lane]  = myl;
    rhsS[(size_t)unit * 12 + lane] = myr;
  }
}

// ---------------------------------------------------------------------------
// Kernel 2: beT[m,k] = be[k,m]
// ---------------------------------------------------------------------------
__global__ __launch_bounds__(256) void k_transpose(
    const float* __restrict__ be, float* __restrict__ beT)
{
  int i = blockIdx.x * 256 + threadIdx.x;  // 262144 total
  int k = i >> 9, m = i & 511;
  beT[m * 512 + k] = be[i];
}

// ---------------------------------------------------------------------------
// Kernel 3: row-wise compaction of mask A (deterministic, ordered by m)
// ---------------------------------------------------------------------------
__global__ void k_build_idx(const float* __restrict__ A,
                            int* __restrict__ nnz, int* __restrict__ cidx)
{
  int j = blockIdx.x;
  int lane = threadIdx.x;  // 64 threads
  unsigned long long lt = (1ull << lane) - 1ull;
  int base = 0;
  for (int c = 0; c < 8; ++c) {
    int m = c * 64 + lane;
    bool p = A[(size_t)j * 512 + m] > 0.5f;
    unsigned long long mask = __ballot(p);
    int pos = base + __popcll(mask & lt);
    if (p && pos < MAXNZ) cidx[j * MAXNZ + pos] = m;
    base += __popcll(mask);
  }
  if (lane == 0) nnz[j] = base > MAXNZ ? MAXNZ : base;
}

// ---------------------------------------------------------------------------
// Kernel 4: column lists
// ---------------------------------------------------------------------------
__global__ void k_build_col(const int* __restrict__ nnz, const int* __restrict__ cidx,
                            int* __restrict__ ccnt, unsigned* __restrict__ colj)
{
  int j = blockIdx.x;
  int lane = threadIdx.x;
  int cnt = nnz[j];
  for (int s = lane; s < cnt; s += 64) {
    int m = cidx[j * MAXNZ + s];
    int pos = atomicAdd(&ccnt[m], 1);
    if (pos < MAXNZ) colj[m * MAXNZ + pos] = (unsigned)j | ((unsigned)s << 16);
  }
}

// ---------------------------------------------------------------------------
// Kernel 5 (v3): product + sigmoid + masked E.
//   R14 evidence: v2 was latency-bound (VALUBusy 41%, occ 38% from 35.8 KB
//   LDS, 4 blocks/CU; 32 narrow dword Ve loads per entry).
//   Fix 1: lhs rows k=tid, tid+256 kept in 24 REGISTERS (loaded once) —
//          lhsL LDS tile (26.6 KB, stride-13) deleted; LDS -> ~9 KB ->
//          8 blocks/CU (100% occ), conflicts gone.
//   Fix 2: E-dot widened: 8 independent dwordx4 Ve loads + float4 sL reads
//          per entry (VMEM instrs 32 -> 8; 256 B contiguous per group;
//          sL reads broadcast across the 4 groups).
// ---------------------------------------------------------------------------
__global__ __launch_bounds__(256) void k_product_E3(
    const float* __restrict__ lhs, const float* __restrict__ rhsS,
    const float* __restrict__ beT, const float* __restrict__ Ve,
    const int* __restrict__ ccnt, const unsigned* __restrict__ colj,
    float* __restrict__ evals)
{
  int b  = blockIdx.x;   // 0..63
  int mc = blockIdx.y;   // 0..31 (16 m-columns each)

  __shared__ __align__(16) float sL[4][512];   // 8 KB
  __shared__ float rh[16 * 12];

  int tid = threadIdx.x;
  int wave = tid >> 6, lane = tid & 63;
  int grp = lane >> 4, lg = lane & 15;

  // lhs rows for k0=tid, k1=tid+256 -> registers (one-time load)
  float l0[12], l1[12];
  {
    const float* p0 = lhs + ((size_t)b * 512 + tid) * 12;
    const float* p1 = lhs + ((size_t)b * 512 + tid + 256) * 12;
    #pragma unroll
    for (int t = 0; t < 12; ++t) { l0[t] = p0[t]; l1[t] = p1[t]; }
  }
  if (tid < 192) rh[tid] = rhsS[((size_t)b * 512 + mc * 16) * 12 + tid];
  __syncthreads();

  for (int g = 0; g < 4; ++g) {
    if (g) __syncthreads();  // previous E phase done reading sL
    #pragma unroll
    for (int mm = 0; mm < 4; ++mm) {
      int m = mc * 16 + g * 4 + mm;
      float p0 = beT[m * 512 + tid];
      float p1 = beT[m * 512 + tid + 256];
      const float* rw = &rh[(g * 4 + mm) * 12];
      #pragma unroll
      for (int t = 0; t < 12; ++t) {
        p0 = fmaf(l0[t], rw[t], p0);
        p1 = fmaf(l1[t], rw[t], p1);
      }
      sL[mm][tid]       = 1.0f / (1.0f + __expf(-p0));
      sL[mm][tid + 256] = 1.0f / (1.0f + __expf(-p1));
    }
    __syncthreads();

    // wave w owns column m = mc*16 + g*4 + w
    int m = mc * 16 + g * 4 + wave;
    int cnt = ccnt[m];
    if (cnt > MAXNZ) cnt = MAXNZ;
    const float4* sw4 = (const float4*)sL[wave];
    for (int e = grp; e < cnt; e += 4) {
      unsigned pk = colj[m * MAXNZ + e];
      int j = pk & 0xffff, slot = (int)(pk >> 16);
      const float4* vr4 = (const float4*)(Ve + (size_t)j * 512);
      float a = 0.f;
      #pragma unroll
      for (int i = 0; i < 8; ++i) {
        float4 v4 = vr4[lg + 16 * i];
        float4 s4 = sw4[lg + 16 * i];
        a = fmaf(v4.x, s4.x, a);
        a = fmaf(v4.y, s4.y, a);
        a = fmaf(v4.z, s4.z, a);
        a = fmaf(v4.w, s4.w, a);
      }
      #pragma unroll
      for (int off = 8; off; off >>= 1) a += __shfl_xor(a, off, 64);
      if (lg == 0) evals[((size_t)b * 512 + j) * MAXNZ + slot] = a;
    }
  }
}

// ---------------------------------------------------------------------------
// Kernel 6 (v11): wave per (b,j). xT imm-offset bf16 gather + fused softmax
//   + f-tiled fmaf GEMM. (R14-measured 104 us, VALUBusy ~90%.)
// XCD swizzle: grid = 8192, sbid = (bid&7)*1024 + (bid>>3) bijective.
// ---------------------------------------------------------------------------
__global__ __launch_bounds__(256) void k_out11(
    const unsigned short* __restrict__ xT,
    const int* __restrict__ nnz, const int* __restrict__ cidx,
    const float* __restrict__ evals,
    const float* __restrict__ K, const float* __restrict__ bias,
    float* __restrict__ out)
{
  int tid = threadIdx.x;
  int wv = tid >> 6, lane = tid & 63;
  int bid = blockIdx.x;
  int sbid = (bid & 7) * 1024 + (bid >> 3);  // bijective on [0,8192)
  int unit = sbid * 4 + wv;                  // b*512 + j
  int b = unit >> 9, j = unit & 511;

  __shared__ float convL[4][12][64];
  __shared__ float valL[4][MAXNZ];
  __shared__ int   idxL[4][MAXNZ];

  int cnt = nnz[j];
  for (int s = lane; s < cnt; s += 64) {
    idxL[wv][s] = cidx[j * MAXNZ + s];
    valL[wv][s] = evals[(size_t)unit * MAXNZ + s];
  }
  // ---- fused masked softmax over this wave's slots (wave-local LDS) ----
  {
    float v0 = lane < cnt        ? valL[wv][lane]      : -__builtin_inff();
    float v1 = (lane + 64) < cnt ? valL[wv][lane + 64] : -__builtin_inff();
    float mx = fmaxf(v0, v1);
    #pragma unroll
    for (int off = 32; off; off >>= 1) mx = fmaxf(mx, __shfl_xor(mx, off, 64));
    float e0 = lane < cnt        ? __expf(v0 - mx) : 0.f;
    float e1 = (lane + 64) < cnt ? __expf(v1 - mx) : 0.f;
    float ssum = wred_sum(e0 + e1);
    float inv = 1.0f / ssum;
    if (lane < cnt)        valL[wv][lane]      = e0 * inv;
    if ((lane + 64) < cnt) valL[wv][lane + 64] = e1 * inv;
  }

  float2 acc[6];
  #pragma unroll
  for (int i = 0; i < 6; ++i) acc[i] = make_float2(0.f, 0.f);

  const unsigned* xb = reinterpret_cast<const unsigned*>(
      xT + (size_t)b * NN * (TT * FF));

  int s = 0;
  for (; s + 1 < cnt; s += 2) {
    int   k0 = idxL[wv][s],     k1 = idxL[wv][s + 1];
    float v0 = valL[wv][s],     v1 = valL[wv][s + 1];
    const unsigned* p0 = xb + k0 * 384 + lane;
    const unsigned* p1 = xb + k1 * 384 + lane;
    unsigned a0 = p0[0],   a1 = p0[64],  a2 = p0[128],
             a3 = p0[192], a4 = p0[256], a5 = p0[320];
    unsigned c0 = p1[0],   c1 = p1[64],  c2 = p1[128],
             c3 = p1[192], c4 = p1[256], c5 = p1[320];
    acc[0].x = fmaf(v0, bflo(a0), acc[0].x); acc[0].y = fmaf(v0, bfhi(a0), acc[0].y);
    acc[1].x = fmaf(v0, bflo(a1), acc[1].x); acc[1].y = fmaf(v0, bfhi(a1), acc[1].y);
    acc[2].x = fmaf(v0, bflo(a2), acc[2].x); acc[2].y = fmaf(v0, bfhi(a2), acc[2].y);
    acc[3].x = fmaf(v0, bflo(a3), acc[3].x); acc[3].y = fmaf(v0, bfhi(a3), acc[3].y);
    acc[4].x = fmaf(v0, bflo(a4), acc[4].x); acc[4].y = fmaf(v0, bfhi(a4), acc[4].y);
    acc[5].x = fmaf(v0, bflo(a5), acc[5].x); acc[5].y = fmaf(v0, bfhi(a5), acc[5].y);
    acc[0].x = fmaf(v1, bflo(c0), acc[0].x); acc[0].y = fmaf(v1, bfhi(c0), acc[0].y);
    acc[1].x = fmaf(v1, bflo(c1), acc[1].x); acc[1].y = fmaf(v1, bfhi(c1), acc[1].y);
    acc[2].x = fmaf(v1, bflo(c2), acc[2].x); acc[2].y = fmaf(v1, bfhi(c2), acc[2].y);
    acc[3].x = fmaf(v1, bflo(c3), acc[3].x); acc[3].y = fmaf(v1, bfhi(c3), acc[3].y);
    acc[4].x = fmaf(v1, bflo(c4), acc[4].x); acc[4].y = fmaf(v1, bfhi(c4), acc[4].y);
    acc[5].x = fmaf(v1, bflo(c5), acc[5].x); acc[5].y = fmaf(v1, bfhi(c5), acc[5].y);
  }
  if (s < cnt) {
    int   k0 = idxL[wv][s];
    float v0 = valL[wv][s];
    const unsigned* p0 = xb + k0 * 384 + lane;
    unsigned a0 = p0[0],   a1 = p0[64],  a2 = p0[128],
             a3 = p0[192], a4 = p0[256], a5 = p0[320];
    acc[0].x = fmaf(v0, bflo(a0), acc[0].x); acc[0].y = fmaf(v0, bfhi(a0), acc[0].y);
    acc[1].x = fmaf(v0, bflo(a1), acc[1].x); acc[1].y = fmaf(v0, bfhi(a1), acc[1].y);
    acc[2].x = fmaf(v0, bflo(a2), acc[2].x); acc[2].y = fmaf(v0, bfhi(a2), acc[2].y);
    acc[3].x = fmaf(v0, bflo(a3), acc[3].x); acc[3].y = fmaf(v0, bfhi(a3), acc[3].y);
    acc[4].x = fmaf(v0, bflo(a4), acc[4].x); acc[4].y = fmaf(v0, bfhi(a4), acc[4].y);
    acc[5].x = fmaf(v0, bflo(a5), acc[5].x); acc[5].y = fmaf(v0, bfhi(a5), acc[5].y);
  }

  int half = lane >> 5, fl = lane & 31;
  #pragma unroll
  for (int i = 0; i < 6; ++i)
    *(float2*)&convL[wv][2 * i + half][fl * 2] = acc[i];

  float bs = bias[lane];
  float o[12];
  #pragma unroll
  for (int t = 0; t < 12; ++t) o[t] = bs;

  __syncthreads();

  #pragma unroll
  for (int ft = 0; ft < 4; ++ft) {
    float kc[16];
    #pragma unroll
    for (int i = 0; i < 16; ++i) kc[i] = K[(ft * 16 + i) * 64 + lane];
    #pragma unroll
    for (int t = 0; t < 12; ++t) {
      const float4* cv = (const float4*)&convL[wv][t][ft * 16];
      float4 c0 = cv[0], c1 = cv[1], c2 = cv[2], c3 = cv[3];
      float o_ = o[t];
      o_ = fmaf(c0.x, kc[0],  o_); o_ = fmaf(c0.y, kc[1],  o_);
      o_ = fmaf(c0.z, kc[2],  o_); o_ = fmaf(c0.w, kc[3],  o_);
      o_ = fmaf(c1.x, kc[4],  o_); o_ = fmaf(c1.y, kc[5],  o_);
      o_ = fmaf(c1.z, kc[6],  o_); o_ = fmaf(c1.w, kc[7],  o_);
      o_ = fmaf(c2.x, kc[8],  o_); o_ = fmaf(c2.y, kc[9],  o_);
      o_ = fmaf(c2.z, kc[10], o_); o_ = fmaf(c2.w, kc[11], o_);
      o_ = fmaf(c3.x, kc[12], o_); o_ = fmaf(c3.y, kc[13], o_);
      o_ = fmaf(c3.z, kc[14], o_); o_ = fmaf(c3.w, kc[15], o_);
      o[t] = o_;
    }
  }

  #pragma unroll
  for (int t = 0; t < 12; ++t)
    out[((size_t)(b * TT + t) * NN + j) * UU + lane] = o[t];
}

// ---------------------------------------------------------------------------
// Kernel 6 fallback (fp32 scalar gather + fused softmax + fmaf phase B)
// ---------------------------------------------------------------------------
__global__ __launch_bounds__(256) void k_out3f(
    const float* __restrict__ x,
    const int* __restrict__ nnz, const int* __restrict__ cidx,
    const float* __restrict__ evals,
    const float* __restrict__ K, const float* __restrict__ bias,
    float* __restrict__ out)
{
  int wv = threadIdx.x >> 6, lane = threadIdx.x & 63;
  int bid = blockIdx.x;
  int sbid = (bid & 7) * 1024 + (bid >> 3);
  int unit = sbid * 4 + wv;
  int b = unit >> 9, j = unit & 511;

  __shared__ float convL[4][12][64];
  __shared__ float valL[4][MAXNZ];
  __shared__ int   idxL[4][MAXNZ];

  int cnt = nnz[j];
  for (int s = lane; s < cnt; s += 64) {
    idxL[wv][s] = cidx[j * MAXNZ + s];
    valL[wv][s] = evals[(size_t)unit * MAXNZ + s];
  }
  {
    float v0 = lane < cnt        ? valL[wv][lane]      : -__builtin_inff();
    float v1 = (lane + 64) < cnt ? valL[wv][lane + 64] : -__builtin_inff();
    float mx = fmaxf(v0, v1);
    #pragma unroll
    for (int off = 32; off; off >>= 1) mx = fmaxf(mx, __shfl_xor(mx, off, 64));
    float e0 = lane < cnt        ? __expf(v0 - mx) : 0.f;
    float e1 = (lane + 64) < cnt ? __expf(v1 - mx) : 0.f;
    float ssum = wred_sum(e0 + e1);
    float inv = 1.0f / ssum;
    if (lane < cnt)        valL[wv][lane]      = e0 * inv;
    if ((lane + 64) < cnt) valL[wv][lane + 64] = e1 * inv;
  }

  float acc[12];
  #pragma unroll
  for (int t = 0; t < 12; ++t) acc[t] = 0.f;

  const float* xb = x + (size_t)b * TT * NN * FF + lane;
  for (int s = 0; s < cnt; ++s) {
    float v = valL[wv][s];
    const float* xk = xb + (size_t)idxL[wv][s] * FF;
    #pragma unroll
    for (int t = 0; t < 12; ++t)
      acc[t] = fmaf(v, xk[(size_t)t * NN * FF], acc[t]);
  }
  #pragma unroll
  for (int t = 0; t < 12; ++t) convL[wv][t][lane] = acc[t];

  float bs = bias[lane];
  float o[12];
  #pragma unroll
  for (int t = 0; t < 12; ++t) o[t] = bs;
  __syncthreads();

  #pragma unroll
  for (int ft = 0; ft < 4; ++ft) {
    float kc[16];
    #pragma unroll
    for (int i = 0; i < 16; ++i) kc[i] = K[(ft * 16 + i) * 64 + lane];
    #pragma unroll
    for (int t = 0; t < 12; ++t) {
      const float4* cv = (const float4*)&convL[wv][t][ft * 16];
      float4 c0 = cv[0], c1 = cv[1], c2 = cv[2], c3 = cv[3];
      float o_ = o[t];
      o_ = fmaf(c0.x, kc[0],  o_); o_ = fmaf(c0.y, kc[1],  o_);
      o_ = fmaf(c0.z, kc[2],  o_); o_ = fmaf(c0.w, kc[3],  o_);
      o_ = fmaf(c1.x, kc[4],  o_); o_ = fmaf(c1.y, kc[5],  o_);
      o_ = fmaf(c1.z, kc[6],  o_); o_ = fmaf(c1.w, kc[7],  o_);
      o_ = fmaf(c2.x, kc[8],  o_); o_ = fmaf(c2.y, kc[9],  o_);
      o_ = fmaf(c2.z, kc[10], o_); o_ = fmaf(c2.w, kc[11], o_);
      o_ = fmaf(c3.x, kc[12], o_); o_ = fmaf(c3.y, kc[13], o_);
      o_ = fmaf(c3.z, kc[14], o_); o_ = fmaf(c3.w, kc[15], o_);
      o[t] = o_;
    }
  }

  #pragma unroll
  for (int t = 0; t < 12; ++t)
    out[((size_t)(b * TT + t) * NN + j) * UU + lane] = o[t];
}

// ---------------------------------------------------------------------------
extern "C" void kernel_launch(void* const* d_in, const int* in_sizes, int n_in,
                              void* d_out, int out_size, void* d_ws, size_t ws_size,
                              hipStream_t stream)
{
  const float* x    = (const float*)d_in[0];  // (B,T,N,F)
  const float* A    = (const float*)d_in[1];  // (N,N)
  const float* W1   = (const float*)d_in[2];  // (T,1)
  const float* W2   = (const float*)d_in[3];  // (F,T)
  const float* W3   = (const float*)d_in[4];  // (F,1)
  const float* Ve   = (const float*)d_in[5];  // (N,N)
  const float* be   = (const float*)d_in[6];  // (N,N)
  const float* K    = (const float*)d_in[7];  // (F,U)
  const float* bias = (const float*)d_in[8];  // (U,)
  float* out = (float*)d_out;

  char* ws = (char*)d_ws;
  float* lhs   = (float*)ws + OF_LHS;
  float* rhsS  = (float*)ws + OF_RHS;
  float* beT   = (float*)ws + OF_BET;
  float* evals = (float*)ws + OF_EVALS;
  int*      nnz  = (int*)(ws + OB_NNZ);
  int*      cidx = (int*)(ws + OB_CIDX);
  int*      ccnt = (int*)(ws + OB_CCNT);
  unsigned* colj = (unsigned*)(ws + OB_COLJ);
  unsigned short* xT = (unsigned short*)(ws + OB_XT);

  const bool use_xt = ws_size >= OB_XT + XT_BYTES;

  hipMemsetAsync(ccnt, 0, NN * sizeof(int), stream);

  // 1. lhs / rhs (+ transposed bf16 copy of x)
  k_lhs_rhs<<<dim3(BB * NN / 4), dim3(256), 0, stream>>>(
      x, W1, W2, W3, lhs, rhsS, use_xt ? xT : nullptr);
  // 2. transpose be
  k_transpose<<<dim3(NN * NN / 256), dim3(256), 0, stream>>>(be, beT);
  // 3. row index lists
  k_build_idx<<<dim3(NN), dim3(64), 0, stream>>>(A, nnz, cidx);
  // 4. column lists
  k_build_col<<<dim3(NN), dim3(64), 0, stream>>>(nnz, cidx, ccnt, colj);
  // 5. product + sigmoid + masked E (v3: register lhs, float4 E-dot)
  k_product_E3<<<dim3(BB, NN / 16), dim3(256), 0, stream>>>(lhs, rhsS, beT, Ve, ccnt, colj, evals);
  // 6. sparse conv + fused softmax + f-tiled output GEMM
  if (use_xt)
    k_out11<<<dim3(BB * NN / 4), dim3(256), 0, stream>>>(xT, nnz, cidx, evals, K, bias, out);
  else
    k_out3f<<<dim3(BB * NN / 4), dim3(256), 0, stream>>>(x, nnz, cidx, evals, K, bias, out);
}

// Round 16
// 219.142 us; speedup vs baseline: 1.2838x; 1.1128x over previous
//
#include <hip/hip_runtime.h>
#include <hip/hip_bf16.h>
#include <cstdint>

// Problem constants
constexpr int BB = 64;    // batch
constexpr int TT = 12;    // time
constexpr int NN = 512;   // nodes
constexpr int FF = 64;    // features
constexpr int UU = 64;    // units
constexpr int MAXNZ = 128;

// ---------------------------------------------------------------------------
// Workspace layout (bytes):
//   floats: lhs 0 / rhs 393216f / beT 786432f / evals 1048576f
//   ints:   nnz 20971520 / cidx 20973568 / ccnt 21235712 / colj 21237760
//   xT (B,N,T,F) bf16 : 21516288, 50331648 B
//   KF (8 frags x 64 lanes x 8 bf16) : 71847936, 8192 B
// ---------------------------------------------------------------------------
constexpr size_t OF_LHS   = 0;
constexpr size_t OF_RHS   = 393216;
constexpr size_t OF_BET   = 786432;
constexpr size_t OF_EVALS = 1048576;
constexpr size_t OB_NNZ   = 20971520;
constexpr size_t OB_CIDX  = 20973568;
constexpr size_t OB_CCNT  = 21235712;
constexpr size_t OB_COLJ  = 21237760;
constexpr size_t OB_XT    = 21516288;
constexpr size_t XT_BYTES = (size_t)BB * NN * TT * FF * 2;  // 50331648
constexpr size_t OB_KF    = 71847936;
constexpr size_t KF_BYTES = 8 * 64 * 8 * 2;                 // 8192

typedef __attribute__((ext_vector_type(8))) short bf16x8;   // 8 bf16 = 4 VGPRs
typedef __attribute__((ext_vector_type(4))) float f32x4;

__device__ __forceinline__ float wred_sum(float v) {
  #pragma unroll
  for (int off = 32; off; off >>= 1) v += __shfl_xor(v, off, 64);
  return v;
}

__device__ __forceinline__ float bflo(unsigned u) {
  return __uint_as_float(u << 16);
}
__device__ __forceinline__ float bfhi(unsigned u) {
  return __uint_as_float(u & 0xFFFF0000u);
}

// ---------------------------------------------------------------------------
// Kernel 1: lhs/rhs reductions; also writes xT[b][n][t][f] bf16
// ---------------------------------------------------------------------------
__global__ __launch_bounds__(256) void k_lhs_rhs(
    const float* __restrict__ x, const float* __restrict__ W1,
    const float* __restrict__ W2, const float* __restrict__ W3,
    float* __restrict__ lhs, float* __restrict__ rhsS,
    unsigned short* __restrict__ xT)   // may be null
{
  int unit = blockIdx.x * 4 + (threadIdx.x >> 6);   // b*512 + n
  int lane = threadIdx.x & 63;
  int b = unit >> 9, n = unit & 511;

  const float* xb = x + ((size_t)b * TT * NN + n) * FF + lane;
  float xv[12];
  #pragma unroll
  for (int t = 0; t < 12; ++t) xv[t] = xb[(size_t)t * NN * FF];

  if (xT) {
    unsigned short* xo = xT + (size_t)unit * (TT * FF) + lane;
    #pragma unroll
    for (int t = 0; t < 12; ++t) {
      __hip_bfloat16 h = __float2bfloat16(xv[t]);   // RTNE
      xo[t * FF] = *reinterpret_cast<unsigned short*>(&h);
    }
  }

  float r1 = 0.f;
  #pragma unroll
  for (int t = 0; t < 12; ++t) r1 += xv[t] * W1[t];

  float w3 = W3[lane];

  float myl = 0.f, myr = 0.f;
  #pragma unroll
  for (int t = 0; t < 12; ++t) {
    float a = r1 * W2[lane * 12 + t];
    float c = xv[t] * w3;
    a = wred_sum(a);
    c = wred_sum(c);
    if (lane == t) { myl = a; myr = c; }
  }
  if (lane < 12) {
    lhs[(size_t)unit * 12 + lane]  = myl;
    rhsS[(size_t)unit * 12 + lane] = myr;
  }
}

// ---------------------------------------------------------------------------
// Kernel 2: beT[m,k] = be[k,m]; extra block builds KF (bf16 K fragments).
//   KF[frag][l][e] = bf16(K[f][u]), frag = kk*4+nt, f = kk*32+(l>>4)*8+e,
//   u = nt*16+(l&15).  Same k-map (k=(l>>4)*8+e) is used for the A-fragment
//   read in k_out12 — k-permutation invariance makes any consistent map OK.
// ---------------------------------------------------------------------------
__global__ __launch_bounds__(256) void k_transpose(
    const float* __restrict__ be, float* __restrict__ beT,
    const float* __restrict__ K, unsigned short* __restrict__ KF)
{
  if (blockIdx.x == NN * NN / 256) {
    if (KF) {
      for (int idx = threadIdx.x; idx < 512; idx += 256) {
        int frag = idx >> 6, l = idx & 63;
        int kk = frag >> 2, nt = frag & 3;
        int u = nt * 16 + (l & 15);
        unsigned short* dst = KF + (size_t)idx * 8;
        for (int e = 0; e < 8; ++e) {
          int f = kk * 32 + (l >> 4) * 8 + e;
          __hip_bfloat16 h = __float2bfloat16(K[f * 64 + u]);
          dst[e] = *reinterpret_cast<unsigned short*>(&h);
        }
      }
    }
    return;
  }
  int i = blockIdx.x * 256 + threadIdx.x;  // 262144 total
  int k = i >> 9, m = i & 511;
  beT[m * 512 + k] = be[i];
}

// ---------------------------------------------------------------------------
// Kernel 3: row-wise compaction of mask A (deterministic, ordered by m)
// ---------------------------------------------------------------------------
__global__ void k_build_idx(const float* __restrict__ A,
                            int* __restrict__ nnz, int* __restrict__ cidx)
{
  int j = blockIdx.x;
  int lane = threadIdx.x;  // 64 threads
  unsigned long long lt = (1ull << lane) - 1ull;
  int base = 0;
  for (int c = 0; c < 8; ++c) {
    int m = c * 64 + lane;
    bool p = A[(size_t)j * 512 + m] > 0.5f;
    unsigned long long mask = __ballot(p);
    int pos = base + __popcll(mask & lt);
    if (p && pos < MAXNZ) cidx[j * MAXNZ + pos] = m;
    base += __popcll(mask);
  }
  if (lane == 0) nnz[j] = base > MAXNZ ? MAXNZ : base;
}

// ---------------------------------------------------------------------------
// Kernel 4: column lists
// ---------------------------------------------------------------------------
__global__ void k_build_col(const int* __restrict__ nnz, const int* __restrict__ cidx,
                            int* __restrict__ ccnt, unsigned* __restrict__ colj)
{
  int j = blockIdx.x;
  int lane = threadIdx.x;
  int cnt = nnz[j];
  for (int s = lane; s < cnt; s += 64) {
    int m = cidx[j * MAXNZ + s];
    int pos = atomicAdd(&ccnt[m], 1);
    if (pos < MAXNZ) colj[m * MAXNZ + pos] = (unsigned)j | ((unsigned)s << 16);
  }
}

// ---------------------------------------------------------------------------
// Kernel 5 (v3, R15-proven): product + sigmoid + masked E.
// ---------------------------------------------------------------------------
__global__ __launch_bounds__(256) void k_product_E3(
    const float* __restrict__ lhs, const float* __restrict__ rhsS,
    const float* __restrict__ beT, const float* __restrict__ Ve,
    const int* __restrict__ ccnt, const unsigned* __restrict__ colj,
    float* __restrict__ evals)
{
  int b  = blockIdx.x;   // 0..63
  int mc = blockIdx.y;   // 0..31 (16 m-columns each)

  __shared__ __align__(16) float sL[4][512];   // 8 KB
  __shared__ float rh[16 * 12];

  int tid = threadIdx.x;
  int wave = tid >> 6, lane = tid & 63;
  int grp = lane >> 4, lg = lane & 15;

  float l0[12], l1[12];
  {
    const float* p0 = lhs + ((size_t)b * 512 + tid) * 12;
    const float* p1 = lhs + ((size_t)b * 512 + tid + 256) * 12;
    #pragma unroll
    for (int t = 0; t < 12; ++t) { l0[t] = p0[t]; l1[t] = p1[t]; }
  }
  if (tid < 192) rh[tid] = rhsS[((size_t)b * 512 + mc * 16) * 12 + tid];
  __syncthreads();

  for (int g = 0; g < 4; ++g) {
    if (g) __syncthreads();
    #pragma unroll
    for (int mm = 0; mm < 4; ++mm) {
      int m = mc * 16 + g * 4 + mm;
      float p0 = beT[m * 512 + tid];
      float p1 = beT[m * 512 + tid + 256];
      const float* rw = &rh[(g * 4 + mm) * 12];
      #pragma unroll
      for (int t = 0; t < 12; ++t) {
        p0 = fmaf(l0[t], rw[t], p0);
        p1 = fmaf(l1[t], rw[t], p1);
      }
      sL[mm][tid]       = 1.0f / (1.0f + __expf(-p0));
      sL[mm][tid + 256] = 1.0f / (1.0f + __expf(-p1));
    }
    __syncthreads();

    int m = mc * 16 + g * 4 + wave;
    int cnt = ccnt[m];
    if (cnt > MAXNZ) cnt = MAXNZ;
    const float4* sw4 = (const float4*)sL[wave];
    for (int e = grp; e < cnt; e += 4) {
      unsigned pk = colj[m * MAXNZ + e];
      int j = pk & 0xffff, slot = (int)(pk >> 16);
      const float4* vr4 = (const float4*)(Ve + (size_t)j * 512);
      float a = 0.f;
      #pragma unroll
      for (int i = 0; i < 8; ++i) {
        float4 v4 = vr4[lg + 16 * i];
        float4 s4 = sw4[lg + 16 * i];
        a = fmaf(v4.x, s4.x, a);
        a = fmaf(v4.y, s4.y, a);
        a = fmaf(v4.z, s4.z, a);
        a = fmaf(v4.w, s4.w, a);
      }
      #pragma unroll
      for (int off = 8; off; off >>= 1) a += __shfl_xor(a, off, 64);
      if (lg == 0) evals[((size_t)b * 512 + j) * MAXNZ + slot] = a;
    }
  }
}

// ---------------------------------------------------------------------------
// Kernel 6 (v12): wave per (b,j). Phase A = v11 (xT bf16 gather + fused
//   softmax).  Phase B = MFMA: conv(12x64,pad16) @ K(64x64) via 8x
//   mfma_f32_16x16x32_bf16 (4 N-tiles x 2 K-steps) — replaces ~1030 VALU/DS
//   instrs with ~80 + 8 MFMA.
//   Layout safety: A/B fragment k-maps chosen identically (k=(l>>4)*8+e) on
//   both operands -> k-permutation invariance; C/D layout is the HW-verified
//   col=lane&15, row=(lane>>4)*4+reg. A rows 12-15 are garbage but only
//   affect D rows 12-15 (never stored). All LDS wave-private: no barriers.
// XCD swizzle: grid = 8192, sbid = (bid&7)*1024 + (bid>>3) bijective.
// ---------------------------------------------------------------------------
__global__ __launch_bounds__(256) void k_out12(
    const unsigned short* __restrict__ xT,
    const int* __restrict__ nnz, const int* __restrict__ cidx,
    const float* __restrict__ evals,
    const unsigned short* __restrict__ KF, const float* __restrict__ bias,
    float* __restrict__ out)
{
  int tid = threadIdx.x;
  int wv = tid >> 6, lane = tid & 63;
  int bid = blockIdx.x;
  int sbid = (bid & 7) * 1024 + (bid >> 3);  // bijective on [0,8192)
  int unit = sbid * 4 + wv;                  // b*512 + j
  int b = unit >> 9, j = unit & 511;

  __shared__ unsigned short convB[4][16][80];  // bf16, row stride 160 B (4-way max)
  __shared__ float valL[4][MAXNZ];
  __shared__ int   idxL[4][MAXNZ];

  int cnt = nnz[j];
  for (int s = lane; s < cnt; s += 64) {
    idxL[wv][s] = cidx[j * MAXNZ + s];
    valL[wv][s] = evals[(size_t)unit * MAXNZ + s];
  }
  // ---- fused masked softmax over this wave's slots (wave-local) ----
  {
    float v0 = lane < cnt        ? valL[wv][lane]      : -__builtin_inff();
    float v1 = (lane + 64) < cnt ? valL[wv][lane + 64] : -__builtin_inff();
    float mx = fmaxf(v0, v1);
    #pragma unroll
    for (int off = 32; off; off >>= 1) mx = fmaxf(mx, __shfl_xor(mx, off, 64));
    float e0 = lane < cnt        ? __expf(v0 - mx) : 0.f;
    float e1 = (lane + 64) < cnt ? __expf(v1 - mx) : 0.f;
    float ssum = wred_sum(e0 + e1);
    float inv = 1.0f / ssum;
    if (lane < cnt)        valL[wv][lane]      = e0 * inv;
    if ((lane + 64) < cnt) valL[wv][lane + 64] = e1 * inv;
  }

  // ---- phase A: bf16 gather from xT (contiguous, imm-offset) ----
  float2 acc[6];
  #pragma unroll
  for (int i = 0; i < 6; ++i) acc[i] = make_float2(0.f, 0.f);

  const unsigned* xb = reinterpret_cast<const unsigned*>(
      xT + (size_t)b * NN * (TT * FF));

  int s = 0;
  for (; s + 1 < cnt; s += 2) {
    int   k0 = idxL[wv][s],     k1 = idxL[wv][s + 1];
    float v0 = valL[wv][s],     v1 = valL[wv][s + 1];
    const unsigned* p0 = xb + k0 * 384 + lane;
    const unsigned* p1 = xb + k1 * 384 + lane;
    unsigned a0 = p0[0],   a1 = p0[64],  a2 = p0[128],
             a3 = p0[192], a4 = p0[256], a5 = p0[320];
    unsigned c0 = p1[0],   c1 = p1[64],  c2 = p1[128],
             c3 = p1[192], c4 = p1[256], c5 = p1[320];
    acc[0].x = fmaf(v0, bflo(a0), acc[0].x); acc[0].y = fmaf(v0, bfhi(a0), acc[0].y);
    acc[1].x = fmaf(v0, bflo(a1), acc[1].x); acc[1].y = fmaf(v0, bfhi(a1), acc[1].y);
    acc[2].x = fmaf(v0, bflo(a2), acc[2].x); acc[2].y = fmaf(v0, bfhi(a2), acc[2].y);
    acc[3].x = fmaf(v0, bflo(a3), acc[3].x); acc[3].y = fmaf(v0, bfhi(a3), acc[3].y);
    acc[4].x = fmaf(v0, bflo(a4), acc[4].x); acc[4].y = fmaf(v0, bfhi(a4), acc[4].y);
    acc[5].x = fmaf(v0, bflo(a5), acc[5].x); acc[5].y = fmaf(v0, bfhi(a5), acc[5].y);
    acc[0].x = fmaf(v1, bflo(c0), acc[0].x); acc[0].y = fmaf(v1, bfhi(c0), acc[0].y);
    acc[1].x = fmaf(v1, bflo(c1), acc[1].x); acc[1].y = fmaf(v1, bfhi(c1), acc[1].y);
    acc[2].x = fmaf(v1, bflo(c2), acc[2].x); acc[2].y = fmaf(v1, bfhi(c2), acc[2].y);
    acc[3].x = fmaf(v1, bflo(c3), acc[3].x); acc[3].y = fmaf(v1, bfhi(c3), acc[3].y);
    acc[4].x = fmaf(v1, bflo(c4), acc[4].x); acc[4].y = fmaf(v1, bfhi(c4), acc[4].y);
    acc[5].x = fmaf(v1, bflo(c5), acc[5].x); acc[5].y = fmaf(v1, bfhi(c5), acc[5].y);
  }
  if (s < cnt) {
    int   k0 = idxL[wv][s];
    float v0 = valL[wv][s];
    const unsigned* p0 = xb + k0 * 384 + lane;
    unsigned a0 = p0[0],   a1 = p0[64],  a2 = p0[128],
             a3 = p0[192], a4 = p0[256], a5 = p0[320];
    acc[0].x = fmaf(v0, bflo(a0), acc[0].x); acc[0].y = fmaf(v0, bfhi(a0), acc[0].y);
    acc[1].x = fmaf(v0, bflo(a1), acc[1].x); acc[1].y = fmaf(v0, bfhi(a1), acc[1].y);
    acc[2].x = fmaf(v0, bflo(a2), acc[2].x); acc[2].y = fmaf(v0, bfhi(a2), acc[2].y);
    acc[3].x = fmaf(v0, bflo(a3), acc[3].x); acc[3].y = fmaf(v0, bfhi(a3), acc[3].y);
    acc[4].x = fmaf(v0, bflo(a4), acc[4].x); acc[4].y = fmaf(v0, bfhi(a4), acc[4].y);
    acc[5].x = fmaf(v0, bflo(a5), acc[5].x); acc[5].y = fmaf(v0, bfhi(a5), acc[5].y);
  }

  // ---- stage conv to LDS as bf16 (acc[i] -> t = 2i+half, f = 2fl,2fl+1) ----
  int half = lane >> 5, fl = lane & 31;
  {
    unsigned short* cb = &convB[wv][0][0];
    #pragma unroll
    for (int i = 0; i < 6; ++i) {
      int t = 2 * i + half;
      __hip_bfloat16 hx = __float2bfloat16(acc[i].x);
      __hip_bfloat16 hy = __float2bfloat16(acc[i].y);
      unsigned pkd = (unsigned)*reinterpret_cast<unsigned short*>(&hx)
                   | ((unsigned)*reinterpret_cast<unsigned short*>(&hy) << 16);
      *reinterpret_cast<unsigned*>(&cb[t * 80 + fl * 2]) = pkd;
    }
  }

  // ---- phase B: 8x MFMA (same-wave LDS write->read, compiler orders) ----
  int arow = lane & 15, agrp = lane >> 4;
  bf16x8 afrag0 = *reinterpret_cast<const bf16x8*>(&convB[wv][arow][agrp * 8]);
  bf16x8 afrag1 = *reinterpret_cast<const bf16x8*>(&convB[wv][arow][32 + agrp * 8]);
  const bf16x8* kf = reinterpret_cast<const bf16x8*>(KF);

  #pragma unroll
  for (int nt = 0; nt < 4; ++nt) {
    f32x4 accT = {0.f, 0.f, 0.f, 0.f};
    accT = __builtin_amdgcn_mfma_f32_16x16x32_bf16(afrag0, kf[(0 * 4 + nt) * 64 + lane], accT, 0, 0, 0);
    accT = __builtin_amdgcn_mfma_f32_16x16x32_bf16(afrag1, kf[(1 * 4 + nt) * 64 + lane], accT, 0, 0, 0);
    int u = nt * 16 + arow;
    float bb = bias[u];
    #pragma unroll
    for (int r = 0; r < 4; ++r) {
      int t = agrp * 4 + r;   // D row = (lane>>4)*4 + reg (HW-verified)
      if (t < 12)
        out[((size_t)(b * TT + t) * NN + j) * UU + u] = accT[r] + bb;
    }
  }
}

// ---------------------------------------------------------------------------
// Kernel 6 fallback (fp32 scalar gather + fused softmax + fmaf phase B)
// ---------------------------------------------------------------------------
__global__ __launch_bounds__(256) void k_out3f(
    const float* __restrict__ x,
    const int* __restrict__ nnz, const int* __restrict__ cidx,
    const float* __restrict__ evals,
    const float* __restrict__ K, const float* __restrict__ bias,
    float* __restrict__ out)
{
  int wv = threadIdx.x >> 6, lane = threadIdx.x & 63;
  int bid = blockIdx.x;
  int sbid = (bid & 7) * 1024 + (bid >> 3);
  int unit = sbid * 4 + wv;
  int b = unit >> 9, j = unit & 511;

  __shared__ float convL[4][12][64];
  __shared__ float valL[4][MAXNZ];
  __shared__ int   idxL[4][MAXNZ];

  int cnt = nnz[j];
  for (int s = lane; s < cnt; s += 64) {
    idxL[wv][s] = cidx[j * MAXNZ + s];
    valL[wv][s] = evals[(size_t)unit * MAXNZ + s];
  }
  {
    float v0 = lane < cnt        ? valL[wv][lane]      : -__builtin_inff();
    float v1 = (lane + 64) < cnt ? valL[wv][lane + 64] : -__builtin_inff();
    float mx = fmaxf(v0, v1);
    #pragma unroll
    for (int off = 32; off; off >>= 1) mx = fmaxf(mx, __shfl_xor(mx, off, 64));
    float e0 = lane < cnt        ? __expf(v0 - mx) : 0.f;
    float e1 = (lane + 64) < cnt ? __expf(v1 - mx) : 0.f;
    float ssum = wred_sum(e0 + e1);
    float inv = 1.0f / ssum;
    if (lane < cnt)        valL[wv][lane]      = e0 * inv;
    if ((lane + 64) < cnt) valL[wv][lane + 64] = e1 * inv;
  }

  float acc[12];
  #pragma unroll
  for (int t = 0; t < 12; ++t) acc[t] = 0.f;

  const float* xb = x + (size_t)b * TT * NN * FF + lane;
  for (int s = 0; s < cnt; ++s) {
    float v = valL[wv][s];
    const float* xk = xb + (size_t)idxL[wv][s] * FF;
    #pragma unroll
    for (int t = 0; t < 12; ++t)
      acc[t] = fmaf(v, xk[(size_t)t * NN * FF], acc[t]);
  }
  #pragma unroll
  for (int t = 0; t < 12; ++t) convL[wv][t][lane] = acc[t];

  float bs = bias[lane];
  float o[12];
  #pragma unroll
  for (int t = 0; t < 12; ++t) o[t] = bs;
  __syncthreads();

  #pragma unroll
  for (int ft = 0; ft < 4; ++ft) {
    float kc[16];
    #pragma unroll
    for (int i = 0; i < 16; ++i) kc[i] = K[(ft * 16 + i) * 64 + lane];
    #pragma unroll
    for (int t = 0; t < 12; ++t) {
      const float4* cv = (const float4*)&convL[wv][t][ft * 16];
      float4 c0 = cv[0], c1 = cv[1], c2 = cv[2], c3 = cv[3];
      float o_ = o[t];
      o_ = fmaf(c0.x, kc[0],  o_); o_ = fmaf(c0.y, kc[1],  o_);
      o_ = fmaf(c0.z, kc[2],  o_); o_ = fmaf(c0.w, kc[3],  o_);
      o_ = fmaf(c1.x, kc[4],  o_); o_ = fmaf(c1.y, kc[5],  o_);
      o_ = fmaf(c1.z, kc[6],  o_); o_ = fmaf(c1.w, kc[7],  o_);
      o_ = fmaf(c2.x, kc[8],  o_); o_ = fmaf(c2.y, kc[9],  o_);
      o_ = fmaf(c2.z, kc[10], o_); o_ = fmaf(c2.w, kc[11], o_);
      o_ = fmaf(c3.x, kc[12], o_); o_ = fmaf(c3.y, kc[13], o_);
      o_ = fmaf(c3.z, kc[14], o_); o_ = fmaf(c3.w, kc[15], o_);
      o[t] = o_;
    }
  }

  #pragma unroll
  for (int t = 0; t < 12; ++t)
    out[((size_t)(b * TT + t) * NN + j) * UU + lane] = o[t];
}

// ---------------------------------------------------------------------------
extern "C" void kernel_launch(void* const* d_in, const int* in_sizes, int n_in,
                              void* d_out, int out_size, void* d_ws, size_t ws_size,
                              hipStream_t stream)
{
  const float* x    = (const float*)d_in[0];  // (B,T,N,F)
  const float* A    = (const float*)d_in[1];  // (N,N)
  const float* W1   = (const float*)d_in[2];  // (T,1)
  const float* W2   = (const float*)d_in[3];  // (F,T)
  const float* W3   = (const float*)d_in[4];  // (F,1)
  const float* Ve   = (const float*)d_in[5];  // (N,N)
  const float* be   = (const float*)d_in[6];  // (N,N)
  const float* K    = (const float*)d_in[7];  // (F,U)
  const float* bias = (const float*)d_in[8];  // (U,)
  float* out = (float*)d_out;

  char* ws = (char*)d_ws;
  float* lhs   = (float*)ws + OF_LHS;
  float* rhsS  = (float*)ws + OF_RHS;
  float* beT   = (float*)ws + OF_BET;
  float* evals = (float*)ws + OF_EVALS;
  int*      nnz  = (int*)(ws + OB_NNZ);
  int*      cidx = (int*)(ws + OB_CIDX);
  int*      ccnt = (int*)(ws + OB_CCNT);
  unsigned* colj = (unsigned*)(ws + OB_COLJ);
  unsigned short* xT = (unsigned short*)(ws + OB_XT);
  unsigned short* KF = (unsigned short*)(ws + OB_KF);

  const bool use_xt = ws_size >= OB_KF + KF_BYTES;

  hipMemsetAsync(ccnt, 0, NN * sizeof(int), stream);

  // 1. lhs / rhs (+ transposed bf16 copy of x)
  k_lhs_rhs<<<dim3(BB * NN / 4), dim3(256), 0, stream>>>(
      x, W1, W2, W3, lhs, rhsS, use_xt ? xT : nullptr);
  // 2. transpose be (+ KF fragment build)
  k_transpose<<<dim3(NN * NN / 256 + 1), dim3(256), 0, stream>>>(
      be, beT, K, use_xt ? KF : nullptr);
  // 3. row index lists
  k_build_idx<<<dim3(NN), dim3(64), 0, stream>>>(A, nnz, cidx);
  // 4. column lists
  k_build_col<<<dim3(NN), dim3(64), 0, stream>>>(nnz, cidx, ccnt, colj);
  // 5. product + sigmoid + masked E (v3)
  k_product_E3<<<dim3(BB, NN / 16), dim3(256), 0, stream>>>(lhs, rhsS, beT, Ve, ccnt, colj, evals);
  // 6. sparse conv + fused softmax + MFMA output GEMM
  if (use_xt)
    k_out12<<<dim3(BB * NN / 4), dim3(256), 0, stream>>>(xT, nnz, cidx, evals, KF, bias, out);
  else
    k_out3f<<<dim3(BB * NN / 4), dim3(256), 0, stream>>>(x, nnz, cidx, evals, K, bias, out);
}